// Round 7
// baseline (156.166 us; speedup 1.0000x reference)
//
#include <hip/hip_runtime.h>
#include <hip/hip_bf16.h>
#include <stdint.h>

#define H 512
#define F 2048
#define E 8
#define NTOK 8192
#define LSTRIDE 4096

typedef __bf16 bf16x8 __attribute__((ext_vector_type(8)));
typedef float f32x4 __attribute__((ext_vector_type(4)));

__device__ __forceinline__ unsigned short f2bf(float f) {
    unsigned u = __builtin_bit_cast(unsigned, f);
    u += 0x7FFFu + ((u >> 16) & 1u);
    return (unsigned short)(u >> 16);
}

__device__ __forceinline__ void gl_lds16(const unsigned short* g, unsigned short* l) {
    __builtin_amdgcn_global_load_lds(
        (const __attribute__((address_space(1))) unsigned int*)g,
        (__attribute__((address_space(3))) unsigned int*)l,
        16, 0, 0);
}

// ---------- merged transpose+convert for W1 and W2 ----------
// W1: [8][512][2048] -> w1t [8][2048][512]; W2: [8][2048][512] -> w2t [8][512][2048]
__global__ void transpose_cvt_kernel(const float* __restrict__ W1, unsigned short* __restrict__ w1t,
                                     const float* __restrict__ W2, unsigned short* __restrict__ w2t) {
    __shared__ unsigned short t[64][72];
    int id = blockIdx.x;
    const float* src; unsigned short* dst; int R, C, r0, c0;
    if (id < 2048) {
        R = 512; C = 2048;
        int z = id >> 8, y = (id >> 5) & 7, xx = id & 31;
        src = W1 + (size_t)z * R * C; dst = w1t + (size_t)z * R * C;
        r0 = y * 64; c0 = xx * 64;
    } else {
        int id2 = id - 2048;
        R = 2048; C = 512;
        int z = id2 >> 8, y = id2 & 31, xx = (id2 >> 5) & 7;
        src = W2 + (size_t)z * R * C; dst = w2t + (size_t)z * R * C;
        r0 = y * 64; c0 = xx * 64;
    }
    int tid = threadIdx.x;
    int lrow = tid >> 4, lc4 = (tid & 15) * 4;
    #pragma unroll
    for (int p = 0; p < 4; ++p) {
        int r = p * 16 + lrow;
        float4 v = *(const float4*)(src + (size_t)(r0 + r) * C + c0 + lc4);
        uint2 u;
        u.x = (unsigned)f2bf(v.x) | ((unsigned)f2bf(v.y) << 16);
        u.y = (unsigned)f2bf(v.z) | ((unsigned)f2bf(v.w) << 16);
        *(uint2*)(&t[r][lc4]) = u;
    }
    __syncthreads();
    int och = tid & 7;
    #pragma unroll
    for (int q = 0; q < 2; ++q) {
        int orow = q * 32 + (tid >> 3);
        unsigned short u[8];
        #pragma unroll
        for (int si = 0; si < 8; ++si) u[si] = t[och * 8 + si][orow];
        uint4 uv;
        uv.x = (unsigned)u[0] | ((unsigned)u[1] << 16);
        uv.y = (unsigned)u[2] | ((unsigned)u[3] << 16);
        uv.z = (unsigned)u[4] | ((unsigned)u[5] << 16);
        uv.w = (unsigned)u[6] | ((unsigned)u[7] << 16);
        *(uint4*)(dst + (size_t)(c0 + orow) * R + r0 + och * 8) = uv;
    }
}

// ---------- router ----------
__global__ void router_kernel(const float* __restrict__ x, const float* __restrict__ Wg,
                              float* __restrict__ gate, int* __restrict__ list,
                              int* __restrict__ cnt, float* __restrict__ pprob) {
    __shared__ float wg[H * E];
    __shared__ float lg[32][8];
    __shared__ int am_l[32];
    __shared__ int rank_l[32];
    __shared__ int eb[8];
    int tid = threadIdx.x;

    #pragma unroll
    for (int p = 0; p < 16; ++p) wg[p * 256 + tid] = Wg[p * 256 + tid];
    __syncthreads();

    int tl = tid >> 3, e = tid & 7;
    int token = blockIdx.x * 32 + tl;
    const float4* x4 = (const float4*)(x + (size_t)token * H);
    float acc = 0.f;
    for (int kq = 0; kq < 128; ++kq) {
        float4 v = x4[kq];
        acc += v.x * wg[(kq * 4 + 0) * 8 + e];
        acc += v.y * wg[(kq * 4 + 1) * 8 + e];
        acc += v.z * wg[(kq * 4 + 2) * 8 + e];
        acc += v.w * wg[(kq * 4 + 3) * 8 + e];
    }
    lg[tl][e] = acc;
    __syncthreads();

    if (tid < 32) {
        float l[8];
        #pragma unroll
        for (int q = 0; q < 8; ++q) l[q] = lg[tid][q];
        float mx = l[0];
        #pragma unroll
        for (int q = 1; q < 8; ++q) mx = fmaxf(mx, l[q]);
        float p[8]; float s = 0.f;
        #pragma unroll
        for (int q = 0; q < 8; ++q) { p[q] = expf(l[q] - mx); s += p[q]; }
        int am = 0; float best = l[0];
        #pragma unroll
        for (int q = 1; q < 8; ++q) if (l[q] > best) { best = l[q]; am = q; }
        float inv = 1.f / s;
        #pragma unroll
        for (int q = 0; q < 8; ++q) lg[tid][q] = p[q] * inv;
        float sp = p[am] * inv;
        gate[blockIdx.x * 32 + tid] = sp / (sp + 1e-8f);
        am_l[tid] = am;
    }
    __syncthreads();

    if (tid < 8) {
        float s = 0.f;
        for (int i = 0; i < 32; ++i) s += lg[i][tid];
        pprob[blockIdx.x * 8 + tid] = s;
        int c = 0;
        for (int i = 0; i < 32; ++i) if (am_l[i] == tid) rank_l[i] = c++;
        eb[tid] = atomicAdd(&cnt[tid], c);
    }
    __syncthreads();

    if (tid < 32) {
        int e2 = am_l[tid];
        int pos = eb[e2] + rank_l[tid];
        if (pos < LSTRIDE) list[e2 * LSTRIDE + pos] = blockIdx.x * 32 + tid;
    }
}

__device__ __forceinline__ void load_ebase(const int* __restrict__ cnt, int* eb) {
    int b = 0;
    #pragma unroll
    for (int q = 0; q < 8; ++q) { eb[q] = b; b += cnt[q]; }
}

// ---------- gather (+ fused lb loss in block 0) ----------
__global__ void gather_kernel(const float* __restrict__ x, const float* __restrict__ gate,
                              const int* __restrict__ list, const int* __restrict__ cnt,
                              const float* __restrict__ pprob,
                              unsigned short* __restrict__ xg, float* __restrict__ gs,
                              int* __restrict__ stok, float* __restrict__ outlb) {
    int eb[8];
    load_ebase(cnt, eb);
    if (blockIdx.x == 0 && threadIdx.x < 8) {
        int t = threadIdx.x;
        float acc = 0.f;
        for (int i = 0; i < 256; ++i) acc += pprob[i * 8 + t];
        float v = acc * (float)cnt[t] * (8.0f / ((float)NTOK * (float)NTOK));
        atomicAdd(outlb, v);   // outlb zeroed by host-side memset
    }
    int p = blockIdx.x * 4 + (threadIdx.x >> 6);
    int lane = threadIdx.x & 63;
    int e = 0;
    #pragma unroll
    for (int q = 1; q < 8; ++q) if (p >= eb[q]) e = q;
    int token = list[e * LSTRIDE + (p - eb[e])];
    const float4* src = (const float4*)(x + (size_t)token * H) + lane * 2;
    float4 a = src[0], b = src[1];
    uint4 u;
    u.x = (unsigned)f2bf(a.x) | ((unsigned)f2bf(a.y) << 16);
    u.y = (unsigned)f2bf(a.z) | ((unsigned)f2bf(a.w) << 16);
    u.z = (unsigned)f2bf(b.x) | ((unsigned)f2bf(b.y) << 16);
    u.w = (unsigned)f2bf(b.z) | ((unsigned)f2bf(b.w) << 16);
    *(uint4*)(xg + (size_t)p * H + lane * 8) = u;
    if (lane == 0) { stok[p] = token; gs[p] = gate[token]; }
}

// ---------- GEMM1: h = relu(xg @ W1t^T + b1), 256x256xBK64, 8 waves, counted-vmcnt dbuf ----------
__global__ __launch_bounds__(512, 2) void gemm1_kernel(
    const unsigned short* __restrict__ xg,    // [NTOK][H] sorted
    const unsigned short* __restrict__ w1t,   // [E][F][H]
    const float* __restrict__ b1,
    const int* __restrict__ cnt,
    unsigned short* __restrict__ hbf)         // [NTOK][F] sorted
{
    int bid = blockIdx.x;
    int e = bid & 7;                 // expert -> XCD
    int idx = bid >> 3;              // 0..127
    int mblk = idx >> 3;             // 0..15, m-major
    int c = cnt[e];
    if (mblk * 256 >= c) return;
    int n0 = (idx & 7) * 256;        // n fastest -> same-XCD A-tile reuse
    int eb[8]; load_ebase(cnt, eb);
    int m0 = eb[e] + mblk * 256;
    int segEnd = eb[e] + c;

    __shared__ unsigned short Al[2][256 * 64];   // 2 x 32 KB
    __shared__ unsigned short Bl[2][256 * 64];   // 2 x 32 KB

    int tid = threadIdx.x, lane = tid & 63, w = tid >> 6;
    // staging: chunk c = li*512 + tid; row = li*64 + (tid>>3); chunk-in-row = tid&7
    int srow = tid >> 3, scic = tid & 7;
    int swz = scic ^ (srow & 7);               // source-side involution

    const unsigned short* asrc[4];
    const unsigned short* bsrc[4];
    #pragma unroll
    for (int i = 0; i < 4; ++i) {
        int row = i * 64 + srow;
        int ar = m0 + row; if (ar > NTOK - 1) ar = NTOK - 1;
        asrc[i] = xg + (size_t)ar * H + swz * 8;
        bsrc[i] = w1t + ((size_t)e * F + n0 + row) * H + swz * 8;
    }

    f32x4 acc[8][4] = {};
    int wr = w >> 2, wc = w & 3;
    int mb = wr * 128, nb = wc * 64;
    int lr = lane & 15, x16 = lane >> 4;
    int sw = (lr & 7) << 4;                    // read-side byte XOR

    // prologue: stage tile 0 (8 loads/thread)
    #pragma unroll
    for (int i = 0; i < 4; ++i) {
        gl_lds16(asrc[i], &Al[0][(i * 512 + tid) * 8]);
        gl_lds16(bsrc[i], &Bl[0][(i * 512 + tid) * 8]);
    }

    int cur = 0;
    #pragma unroll
    for (int t = 0; t < 8; ++t) {
        if (t < 7) {
            int k0 = (t + 1) * 64;
            #pragma unroll
            for (int i = 0; i < 4; ++i) {
                gl_lds16(asrc[i] + k0, &Al[cur ^ 1][(i * 512 + tid) * 8]);
                gl_lds16(bsrc[i] + k0, &Bl[cur ^ 1][(i * 512 + tid) * 8]);
            }
            asm volatile("s_waitcnt vmcnt(8)" ::: "memory");  // tile t landed; t+1 in flight
        } else {
            asm volatile("s_waitcnt vmcnt(0)" ::: "memory");
        }
        __builtin_amdgcn_s_barrier();
        #pragma unroll
        for (int kk = 0; kk < 2; ++kk) {
            int co = (kk * 64 + x16 * 16) ^ sw;
            bf16x8 a[8], b[4];
            #pragma unroll
            for (int i = 0; i < 8; ++i)
                a[i] = *(const bf16x8*)((const char*)Al[cur] + (mb + i * 16 + lr) * 128 + co);
            #pragma unroll
            for (int j = 0; j < 4; ++j)
                b[j] = *(const bf16x8*)((const char*)Bl[cur] + (nb + j * 16 + lr) * 128 + co);
            #pragma unroll
            for (int i = 0; i < 8; ++i)
                #pragma unroll
                for (int j = 0; j < 4; ++j)
                    acc[i][j] = __builtin_amdgcn_mfma_f32_16x16x32_bf16(b[j], a[i], acc[i][j], 0, 0, 0);
        }
        asm volatile("s_waitcnt lgkmcnt(0)" ::: "memory");
        __builtin_amdgcn_s_barrier();
        cur ^= 1;
    }

    // epilogue: lane holds 4 consecutive F-cols of one token -> 8B packed stores
    int w4 = x16 * 4;
    #pragma unroll
    for (int j = 0; j < 4; ++j) {
        int gc = n0 + nb + j * 16 + w4;
        float4 bias = *(const float4*)(b1 + e * F + gc);
        #pragma unroll
        for (int i = 0; i < 8; ++i) {
            int p = m0 + mb + i * 16 + lr;
            if (p < segEnd) {
                float v0 = acc[i][j][0] + bias.x; v0 = v0 > 0.f ? v0 : 0.f;
                float v1 = acc[i][j][1] + bias.y; v1 = v1 > 0.f ? v1 : 0.f;
                float v2 = acc[i][j][2] + bias.z; v2 = v2 > 0.f ? v2 : 0.f;
                float v3 = acc[i][j][3] + bias.w; v3 = v3 > 0.f ? v3 : 0.f;
                uint2 pk;
                pk.x = (unsigned)f2bf(v0) | ((unsigned)f2bf(v1) << 16);
                pk.y = (unsigned)f2bf(v2) | ((unsigned)f2bf(v3) << 16);
                *(uint2*)(hbf + (size_t)p * F + gc) = pk;
            }
        }
    }
}

// ---------- GEMM2: out = gate*(h @ W2t^T + b2) scattered, 128x128xBK32, 4 blocks/CU ----------
__global__ __launch_bounds__(256, 4) void gemm2_kernel(
    const unsigned short* __restrict__ hbf,   // [NTOK][F] sorted
    const unsigned short* __restrict__ w2t,   // [E][H][F]
    const float* __restrict__ b2,
    const int* __restrict__ cnt,
    const float* __restrict__ gs, const int* __restrict__ stok,
    float* __restrict__ out)                  // [NTOK][H] token order
{
    int bid = blockIdx.x;
    int e = bid & 7;
    int idx = bid >> 3;              // 0..127
    int mblk = idx >> 2;             // 0..31
    int c = cnt[e];
    if (mblk * 128 >= c) return;
    int n0 = (idx & 3) * 128;
    int eb[8]; load_ebase(cnt, eb);
    int m0 = eb[e] + mblk * 128;
    int segEnd = eb[e] + c;

    __shared__ unsigned short Al[2][128 * 32];   // 2 x 8 KB
    __shared__ unsigned short Bl[2][128 * 32];   // 2 x 8 KB
    __shared__ int stokL[128];
    __shared__ float gsL[128];

    int tid = threadIdx.x, lane = tid & 63, w = tid >> 6;
    if (tid < 128) {
        int p = m0 + tid;
        int pc = p > NTOK - 1 ? NTOK - 1 : p;
        stokL[tid] = stok[pc];
        gsL[tid] = gs[pc];
    }
    // staging: chunk c = li*256 + tid; row = li*64 + (tid>>2); chunk-in-row = tid&3
    int srow = tid >> 2, scic = tid & 3;
    int swz = scic ^ (srow & 3);

    const unsigned short* asrc[2];
    const unsigned short* bsrc[2];
    #pragma unroll
    for (int i = 0; i < 2; ++i) {
        int row = i * 64 + srow;
        int ar = m0 + row; if (ar > NTOK - 1) ar = NTOK - 1;
        asrc[i] = hbf + (size_t)ar * F + swz * 8;
        bsrc[i] = w2t + ((size_t)e * H + n0 + row) * F + swz * 8;
    }

    f32x4 acc[4][4] = {};
    int mb = (w >> 1) * 64, nb = (w & 1) * 64;
    int lr = lane & 15, x16 = lane >> 4;
    int sw2 = lr & 3;

    // prologue: stage tile 0 (4 loads/thread)
    #pragma unroll
    for (int i = 0; i < 2; ++i) {
        gl_lds16(asrc[i], &Al[0][(i * 256 + tid) * 8]);
        gl_lds16(bsrc[i], &Bl[0][(i * 256 + tid) * 8]);
    }

    int cur = 0;
    #pragma unroll 4
    for (int t = 0; t < 64; ++t) {
        if (t < 63) {
            int k0 = (t + 1) * 32;
            #pragma unroll
            for (int i = 0; i < 2; ++i) {
                gl_lds16(asrc[i] + k0, &Al[cur ^ 1][(i * 256 + tid) * 8]);
                gl_lds16(bsrc[i] + k0, &Bl[cur ^ 1][(i * 256 + tid) * 8]);
            }
            asm volatile("s_waitcnt vmcnt(4)" ::: "memory");
        } else {
            asm volatile("s_waitcnt vmcnt(0)" ::: "memory");
        }
        __builtin_amdgcn_s_barrier();
        int co = (x16 ^ sw2) << 4;
        bf16x8 a[4], b[4];
        #pragma unroll
        for (int i = 0; i < 4; ++i)
            a[i] = *(const bf16x8*)((const char*)Al[cur] + (mb + i * 16 + lr) * 64 + co);
        #pragma unroll
        for (int j = 0; j < 4; ++j)
            b[j] = *(const bf16x8*)((const char*)Bl[cur] + (nb + j * 16 + lr) * 64 + co);
        #pragma unroll
        for (int i = 0; i < 4; ++i)
            #pragma unroll
            for (int j = 0; j < 4; ++j)
                acc[i][j] = __builtin_amdgcn_mfma_f32_16x16x32_bf16(b[j], a[i], acc[i][j], 0, 0, 0);
        asm volatile("s_waitcnt lgkmcnt(0)" ::: "memory");
        __builtin_amdgcn_s_barrier();
        cur ^= 1;
    }

    // epilogue: lane holds 4 consecutive H-cols of one token -> float4 stores
    int w4 = x16 * 4;
    #pragma unroll
    for (int i = 0; i < 4; ++i) {
        int rl = mb + i * 16 + lr;
        int p = m0 + rl;
        if (p < segEnd) {
            int tok = stokL[rl];
            float g = gsL[rl];
            #pragma unroll
            for (int j = 0; j < 4; ++j) {
                int gc = n0 + nb + j * 16 + w4;
                float4 bias = *(const float4*)(b2 + e * H + gc);
                float4 res;
                res.x = g * (acc[i][j][0] + bias.x);
                res.y = g * (acc[i][j][1] + bias.y);
                res.z = g * (acc[i][j][2] + bias.z);
                res.w = g * (acc[i][j][3] + bias.w);
                *(float4*)(out + (size_t)tok * H + gc) = res;
            }
        }
    }
}

extern "C" void kernel_launch(void* const* d_in, const int* in_sizes, int n_in,
                              void* d_out, int out_size, void* d_ws, size_t ws_size,
                              hipStream_t stream) {
    const float* x  = (const float*)d_in[0];
    const float* Wg = (const float*)d_in[1];
    const float* W1 = (const float*)d_in[2];
    const float* b1 = (const float*)d_in[3];
    const float* W2 = (const float*)d_in[4];
    const float* b2 = (const float*)d_in[5];
    float* out = (float*)d_out;

    char* ws = (char*)d_ws;
    unsigned short* xg  = (unsigned short*)(ws + 0);          //  8 MB
    unsigned short* w1t = (unsigned short*)(ws + 8388608);    // 16 MB
    unsigned short* w2t = (unsigned short*)(ws + 25165824);   // 16 MB
    unsigned short* hbf = (unsigned short*)(ws + 41943040);   // 32 MB
    float* gate = (float*)(ws + 75497472);                    // 32 KB
    float* gs   = (float*)(ws + 75530240);                    // 32 KB
    int* stok   = (int*)(ws + 75563008);                      // 32 KB
    int* list   = (int*)(ws + 75595776);                      // 128 KB
    int* cnt    = (int*)(ws + 75726848);                      // 64 B
    float* pprob= (float*)(ws + 75726976);                    // 8 KB

    float* outlb = out + (size_t)NTOK * H;
    hipMemsetAsync(cnt, 0, 8 * sizeof(int), stream);
    hipMemsetAsync(outlb, 0, sizeof(float), stream);
    transpose_cvt_kernel<<<4096, 256, 0, stream>>>(W1, w1t, W2, w2t);
    router_kernel<<<256, 256, 0, stream>>>(x, Wg, gate, list, cnt, pprob);
    gather_kernel<<<2048, 256, 0, stream>>>(x, gate, list, cnt, pprob, xg, gs, stok, outlb);
    gemm1_kernel<<<1024, 512, 0, stream>>>(xg, w1t, b1, cnt, hbf);
    gemm2_kernel<<<1024, 256, 0, stream>>>(hbf, w2t, b2, cnt, gs, stok, out);
}

// Round 8
// 138.148 us; speedup vs baseline: 1.1304x; 1.1304x over previous
//
#include <hip/hip_runtime.h>
#include <hip/hip_bf16.h>
#include <stdint.h>

#define H 512
#define F 2048
#define E 8
#define NTOK 8192
#define LSTRIDE 4096

typedef __bf16 bf16x8 __attribute__((ext_vector_type(8)));
typedef float f32x4 __attribute__((ext_vector_type(4)));

__device__ __forceinline__ unsigned short f2bf(float f) {
    unsigned u = __builtin_bit_cast(unsigned, f);
    u += 0x7FFFu + ((u >> 16) & 1u);
    return (unsigned short)(u >> 16);
}

__device__ __forceinline__ void gl_lds16(const unsigned short* g, unsigned short* l) {
    __builtin_amdgcn_global_load_lds(
        (const __attribute__((address_space(1))) unsigned int*)g,
        (__attribute__((address_space(3))) unsigned int*)l,
        16, 0, 0);
}

// ---------- merged transpose+convert for W1 and W2 ----------
__global__ void transpose_cvt_kernel(const float* __restrict__ W1, unsigned short* __restrict__ w1t,
                                     const float* __restrict__ W2, unsigned short* __restrict__ w2t) {
    __shared__ unsigned short t[64][72];
    int id = blockIdx.x;
    const float* src; unsigned short* dst; int R, C, r0, c0;
    if (id < 2048) {
        R = 512; C = 2048;
        int z = id >> 8, y = (id >> 5) & 7, xx = id & 31;
        src = W1 + (size_t)z * R * C; dst = w1t + (size_t)z * R * C;
        r0 = y * 64; c0 = xx * 64;
    } else {
        int id2 = id - 2048;
        R = 2048; C = 512;
        int z = id2 >> 8, y = id2 & 31, xx = (id2 >> 5) & 7;
        src = W2 + (size_t)z * R * C; dst = w2t + (size_t)z * R * C;
        r0 = y * 64; c0 = xx * 64;
    }
    int tid = threadIdx.x;
    int lrow = tid >> 4, lc4 = (tid & 15) * 4;
    #pragma unroll
    for (int p = 0; p < 4; ++p) {
        int r = p * 16 + lrow;
        float4 v = *(const float4*)(src + (size_t)(r0 + r) * C + c0 + lc4);
        uint2 u;
        u.x = (unsigned)f2bf(v.x) | ((unsigned)f2bf(v.y) << 16);
        u.y = (unsigned)f2bf(v.z) | ((unsigned)f2bf(v.w) << 16);
        *(uint2*)(&t[r][lc4]) = u;
    }
    __syncthreads();
    int och = tid & 7;
    #pragma unroll
    for (int q = 0; q < 2; ++q) {
        int orow = q * 32 + (tid >> 3);
        unsigned short u[8];
        #pragma unroll
        for (int si = 0; si < 8; ++si) u[si] = t[och * 8 + si][orow];
        uint4 uv;
        uv.x = (unsigned)u[0] | ((unsigned)u[1] << 16);
        uv.y = (unsigned)u[2] | ((unsigned)u[3] << 16);
        uv.z = (unsigned)u[4] | ((unsigned)u[5] << 16);
        uv.w = (unsigned)u[6] | ((unsigned)u[7] << 16);
        *(uint4*)(dst + (size_t)(c0 + orow) * R + r0 + och * 8) = uv;
    }
}

// ---------- router ----------
__global__ void router_kernel(const float* __restrict__ x, const float* __restrict__ Wg,
                              float* __restrict__ gate, int* __restrict__ list,
                              int* __restrict__ cnt, float* __restrict__ pprob) {
    __shared__ float wg[H * E];
    __shared__ float lg[32][8];
    __shared__ int am_l[32];
    __shared__ int rank_l[32];
    __shared__ int eb[8];
    int tid = threadIdx.x;

    #pragma unroll
    for (int p = 0; p < 16; ++p) wg[p * 256 + tid] = Wg[p * 256 + tid];
    __syncthreads();

    int tl = tid >> 3, e = tid & 7;
    int token = blockIdx.x * 32 + tl;
    const float4* x4 = (const float4*)(x + (size_t)token * H);
    float acc = 0.f;
    for (int kq = 0; kq < 128; ++kq) {
        float4 v = x4[kq];
        acc += v.x * wg[(kq * 4 + 0) * 8 + e];
        acc += v.y * wg[(kq * 4 + 1) * 8 + e];
        acc += v.z * wg[(kq * 4 + 2) * 8 + e];
        acc += v.w * wg[(kq * 4 + 3) * 8 + e];
    }
    lg[tl][e] = acc;
    __syncthreads();

    if (tid < 32) {
        float l[8];
        #pragma unroll
        for (int q = 0; q < 8; ++q) l[q] = lg[tid][q];
        float mx = l[0];
        #pragma unroll
        for (int q = 1; q < 8; ++q) mx = fmaxf(mx, l[q]);
        float p[8]; float s = 0.f;
        #pragma unroll
        for (int q = 0; q < 8; ++q) { p[q] = expf(l[q] - mx); s += p[q]; }
        int am = 0; float best = l[0];
        #pragma unroll
        for (int q = 1; q < 8; ++q) if (l[q] > best) { best = l[q]; am = q; }
        float inv = 1.f / s;
        #pragma unroll
        for (int q = 0; q < 8; ++q) lg[tid][q] = p[q] * inv;
        float sp = p[am] * inv;
        gate[blockIdx.x * 32 + tid] = sp / (sp + 1e-8f);
        am_l[tid] = am;
    }
    __syncthreads();

    if (tid < 8) {
        float s = 0.f;
        for (int i = 0; i < 32; ++i) s += lg[i][tid];
        pprob[blockIdx.x * 8 + tid] = s;
        int c = 0;
        for (int i = 0; i < 32; ++i) if (am_l[i] == tid) rank_l[i] = c++;
        eb[tid] = atomicAdd(&cnt[tid], c);
    }
    __syncthreads();

    if (tid < 32) {
        int e2 = am_l[tid];
        int pos = eb[e2] + rank_l[tid];
        if (pos < LSTRIDE) list[e2 * LSTRIDE + pos] = blockIdx.x * 32 + tid;
    }
}

__device__ __forceinline__ void load_ebase(const int* __restrict__ cnt, int* eb) {
    int b = 0;
    #pragma unroll
    for (int q = 0; q < 8; ++q) { eb[q] = b; b += cnt[q]; }
}

// ---------- gather (+ fused lb loss in block 0) ----------
__global__ void gather_kernel(const float* __restrict__ x, const float* __restrict__ gate,
                              const int* __restrict__ list, const int* __restrict__ cnt,
                              const float* __restrict__ pprob,
                              unsigned short* __restrict__ xg, float* __restrict__ gs,
                              int* __restrict__ stok, float* __restrict__ outlb) {
    int eb[8];
    load_ebase(cnt, eb);
    if (blockIdx.x == 0 && threadIdx.x < 8) {
        int t = threadIdx.x;
        float acc = 0.f;
        for (int i = 0; i < 256; ++i) acc += pprob[i * 8 + t];
        float v = acc * (float)cnt[t] * (8.0f / ((float)NTOK * (float)NTOK));
        atomicAdd(outlb, v);
    }
    int p = blockIdx.x * 4 + (threadIdx.x >> 6);
    int lane = threadIdx.x & 63;
    int e = 0;
    #pragma unroll
    for (int q = 1; q < 8; ++q) if (p >= eb[q]) e = q;
    int token = list[e * LSTRIDE + (p - eb[e])];
    const float4* src = (const float4*)(x + (size_t)token * H) + lane * 2;
    float4 a = src[0], b = src[1];
    uint4 u;
    u.x = (unsigned)f2bf(a.x) | ((unsigned)f2bf(a.y) << 16);
    u.y = (unsigned)f2bf(a.z) | ((unsigned)f2bf(a.w) << 16);
    u.z = (unsigned)f2bf(b.x) | ((unsigned)f2bf(b.y) << 16);
    u.w = (unsigned)f2bf(b.z) | ((unsigned)f2bf(b.w) << 16);
    *(uint4*)(xg + (size_t)p * H + lane * 8) = u;
    if (lane == 0) { stok[p] = token; gs[p] = gate[token]; }
}

// ---------- GEMM1: h = relu(xg @ W1t^T + b1), 256x256xBK64, 8 waves, 1-barrier T3 loop ----------
__global__ __launch_bounds__(512, 1) void gemm1_kernel(
    const unsigned short* __restrict__ xg,    // [NTOK][H] sorted
    const unsigned short* __restrict__ w1t,   // [E][F][H]
    const float* __restrict__ b1,
    const int* __restrict__ cnt,
    unsigned short* __restrict__ hbf)         // [NTOK][F] sorted
{
    int bid = blockIdx.x;
    int e = bid & 7;                 // expert -> XCD
    int idx = bid >> 3;              // 0..127
    int mblk = idx >> 3;             // 0..15, m-major
    int c = cnt[e];
    if (mblk * 256 >= c) return;
    int n0 = (idx & 7) * 256;        // n fastest -> same-XCD A-tile reuse
    int eb[8]; load_ebase(cnt, eb);
    int m0 = eb[e] + mblk * 256;
    int segEnd = eb[e] + c;

    __shared__ unsigned short Al[2][256 * 64];   // 2 x 32 KB
    __shared__ unsigned short Bl[2][256 * 64];   // 2 x 32 KB

    int tid = threadIdx.x, lane = tid & 63, w = tid >> 6;
    int srow = tid >> 3, scic = tid & 7;
    int swz = scic ^ (srow & 7);               // source-side involution

    const unsigned short* asrc[4];
    const unsigned short* bsrc[4];
    #pragma unroll
    for (int i = 0; i < 4; ++i) {
        int row = i * 64 + srow;
        int ar = m0 + row; if (ar > NTOK - 1) ar = NTOK - 1;
        asrc[i] = xg + (size_t)ar * H + swz * 8;
        bsrc[i] = w1t + ((size_t)e * F + n0 + row) * H + swz * 8;
    }

    f32x4 acc[8][4] = {};
    int wr = w >> 2, wc = w & 3;
    int mb = wr * 128, nb = wc * 64;
    int lr = lane & 15, x16 = lane >> 4;
    int sw = (lr & 7) << 4;                    // read-side byte XOR

    // prologue: stage tile 0, drain, barrier
    #pragma unroll
    for (int i = 0; i < 4; ++i) {
        gl_lds16(asrc[i], &Al[0][(i * 512 + tid) * 8]);
        gl_lds16(bsrc[i], &Bl[0][(i * 512 + tid) * 8]);
    }
    asm volatile("s_waitcnt vmcnt(0)" ::: "memory");
    __builtin_amdgcn_s_barrier();

    int cur = 0;
    #pragma unroll
    for (int t = 0; t < 8; ++t) {
        // issue next tile's stage FIRST (flies during ds_read + MFMA)
        if (t < 7) {
            int k0 = (t + 1) * 64;
            #pragma unroll
            for (int i = 0; i < 4; ++i) {
                gl_lds16(asrc[i] + k0, &Al[cur ^ 1][(i * 512 + tid) * 8]);
                gl_lds16(bsrc[i] + k0, &Bl[cur ^ 1][(i * 512 + tid) * 8]);
            }
        }
        // compute on buf[cur]
        #pragma unroll
        for (int kk = 0; kk < 2; ++kk) {
            int co = (kk * 64 + x16 * 16) ^ sw;
            bf16x8 a[8], b[4];
            #pragma unroll
            for (int i = 0; i < 8; ++i)
                a[i] = *(const bf16x8*)((const char*)Al[cur] + (mb + i * 16 + lr) * 128 + co);
            #pragma unroll
            for (int j = 0; j < 4; ++j)
                b[j] = *(const bf16x8*)((const char*)Bl[cur] + (nb + j * 16 + lr) * 128 + co);
            #pragma unroll
            for (int i = 0; i < 8; ++i)
                #pragma unroll
                for (int j = 0; j < 4; ++j)
                    acc[i][j] = __builtin_amdgcn_mfma_f32_16x16x32_bf16(b[j], a[i], acc[i][j], 0, 0, 0);
        }
        if (t < 7) {
            asm volatile("s_waitcnt lgkmcnt(0)" ::: "memory");  // my reads of buf[cur] done
            __builtin_amdgcn_sched_barrier(0);                   // rule #18 fence
            asm volatile("s_waitcnt vmcnt(0)" ::: "memory");     // next tile landed (late drain)
            __builtin_amdgcn_s_barrier();                        // single barrier per K-step
            cur ^= 1;
        }
    }

    // epilogue: lane holds 4 consecutive F-cols of one token -> 8B packed stores
    int w4 = x16 * 4;
    #pragma unroll
    for (int j = 0; j < 4; ++j) {
        int gc = n0 + nb + j * 16 + w4;
        float4 bias = *(const float4*)(b1 + e * F + gc);
        #pragma unroll
        for (int i = 0; i < 8; ++i) {
            int p = m0 + mb + i * 16 + lr;
            if (p < segEnd) {
                float v0 = acc[i][j][0] + bias.x; v0 = v0 > 0.f ? v0 : 0.f;
                float v1 = acc[i][j][1] + bias.y; v1 = v1 > 0.f ? v1 : 0.f;
                float v2 = acc[i][j][2] + bias.z; v2 = v2 > 0.f ? v2 : 0.f;
                float v3 = acc[i][j][3] + bias.w; v3 = v3 > 0.f ? v3 : 0.f;
                uint2 pk;
                pk.x = (unsigned)f2bf(v0) | ((unsigned)f2bf(v1) << 16);
                pk.y = (unsigned)f2bf(v2) | ((unsigned)f2bf(v3) << 16);
                *(uint2*)(hbf + (size_t)p * F + gc) = pk;
            }
        }
    }
}

// ---------- GEMM2: out = gate*(h @ W2t^T + b2) scattered, 128x128xBK64, 1-barrier T3 loop ----------
__global__ __launch_bounds__(256, 2) void gemm2_kernel(
    const unsigned short* __restrict__ hbf,   // [NTOK][F] sorted
    const unsigned short* __restrict__ w2t,   // [E][H][F]
    const float* __restrict__ b2,
    const int* __restrict__ cnt,
    const float* __restrict__ gs, const int* __restrict__ stok,
    float* __restrict__ out)                  // [NTOK][H] token order
{
    int bid = blockIdx.x;
    int e = bid & 7;
    int idx = bid >> 3;              // 0..127
    int mblk = idx >> 2;             // 0..31
    int c = cnt[e];
    if (mblk * 128 >= c) return;
    int n0 = (idx & 3) * 128;
    int eb[8]; load_ebase(cnt, eb);
    int m0 = eb[e] + mblk * 128;
    int segEnd = eb[e] + c;

    __shared__ unsigned short Al[2][128 * 64];   // 2 x 16 KB
    __shared__ unsigned short Bl[2][128 * 64];   // 2 x 16 KB
    __shared__ int stokL[128];
    __shared__ float gsL[128];

    int tid = threadIdx.x, lane = tid & 63, w = tid >> 6;
    if (tid < 128) {
        int p = m0 + tid;
        int pc = p > NTOK - 1 ? NTOK - 1 : p;
        stokL[tid] = stok[pc];
        gsL[tid] = gs[pc];
    }
    int srow = tid >> 3, scic = tid & 7;
    int swz = scic ^ (srow & 7);

    const unsigned short* asrc[4];
    const unsigned short* bsrc[4];
    #pragma unroll
    for (int i = 0; i < 4; ++i) {
        int row = i * 32 + srow;
        int ar = m0 + row; if (ar > NTOK - 1) ar = NTOK - 1;
        asrc[i] = hbf + (size_t)ar * F + swz * 8;
        bsrc[i] = w2t + ((size_t)e * H + n0 + row) * F + swz * 8;
    }

    f32x4 acc[4][4] = {};
    int mb = (w >> 1) * 64, nb = (w & 1) * 64;
    int lr = lane & 15, x16 = lane >> 4;
    int sw = (lr & 7) << 4;

    // prologue
    #pragma unroll
    for (int i = 0; i < 4; ++i) {
        gl_lds16(asrc[i], &Al[0][(i * 256 + tid) * 8]);
        gl_lds16(bsrc[i], &Bl[0][(i * 256 + tid) * 8]);
    }
    asm volatile("s_waitcnt vmcnt(0)" ::: "memory");
    __builtin_amdgcn_s_barrier();

    int cur = 0;
    #pragma unroll 2
    for (int t = 0; t < 32; ++t) {
        if (t < 31) {
            int k0 = (t + 1) * 64;
            #pragma unroll
            for (int i = 0; i < 4; ++i) {
                gl_lds16(asrc[i] + k0, &Al[cur ^ 1][(i * 256 + tid) * 8]);
                gl_lds16(bsrc[i] + k0, &Bl[cur ^ 1][(i * 256 + tid) * 8]);
            }
        }
        #pragma unroll
        for (int kk = 0; kk < 2; ++kk) {
            int co = (kk * 64 + x16 * 16) ^ sw;
            bf16x8 a[4], b[4];
            #pragma unroll
            for (int i = 0; i < 4; ++i)
                a[i] = *(const bf16x8*)((const char*)Al[cur] + (mb + i * 16 + lr) * 128 + co);
            #pragma unroll
            for (int j = 0; j < 4; ++j)
                b[j] = *(const bf16x8*)((const char*)Bl[cur] + (nb + j * 16 + lr) * 128 + co);
            #pragma unroll
            for (int i = 0; i < 4; ++i)
                #pragma unroll
                for (int j = 0; j < 4; ++j)
                    acc[i][j] = __builtin_amdgcn_mfma_f32_16x16x32_bf16(b[j], a[i], acc[i][j], 0, 0, 0);
        }
        if (t < 31) {
            asm volatile("s_waitcnt lgkmcnt(0)" ::: "memory");
            __builtin_amdgcn_sched_barrier(0);
            asm volatile("s_waitcnt vmcnt(0)" ::: "memory");
            __builtin_amdgcn_s_barrier();
            cur ^= 1;
        }
    }

    // epilogue: lane holds 4 consecutive H-cols of one token -> float4 stores
    int w4 = x16 * 4;
    #pragma unroll
    for (int i = 0; i < 4; ++i) {
        int rl = mb + i * 16 + lr;
        int p = m0 + rl;
        if (p < segEnd) {
            int tok = stokL[rl];
            float g = gsL[rl];
            #pragma unroll
            for (int j = 0; j < 4; ++j) {
                int gc = n0 + nb + j * 16 + w4;
                float4 bias = *(const float4*)(b2 + e * H + gc);
                float4 res;
                res.x = g * (acc[i][j][0] + bias.x);
                res.y = g * (acc[i][j][1] + bias.y);
                res.z = g * (acc[i][j][2] + bias.z);
                res.w = g * (acc[i][j][3] + bias.w);
                *(float4*)(out + (size_t)tok * H + gc) = res;
            }
        }
    }
}

extern "C" void kernel_launch(void* const* d_in, const int* in_sizes, int n_in,
                              void* d_out, int out_size, void* d_ws, size_t ws_size,
                              hipStream_t stream) {
    const float* x  = (const float*)d_in[0];
    const float* Wg = (const float*)d_in[1];
    const float* W1 = (const float*)d_in[2];
    const float* b1 = (const float*)d_in[3];
    const float* W2 = (const float*)d_in[4];
    const float* b2 = (const float*)d_in[5];
    float* out = (float*)d_out;

    char* ws = (char*)d_ws;
    unsigned short* xg  = (unsigned short*)(ws + 0);          //  8 MB
    unsigned short* w1t = (unsigned short*)(ws + 8388608);    // 16 MB
    unsigned short* w2t = (unsigned short*)(ws + 25165824);   // 16 MB
    unsigned short* hbf = (unsigned short*)(ws + 41943040);   // 32 MB
    float* gate = (float*)(ws + 75497472);                    // 32 KB
    float* gs   = (float*)(ws + 75530240);                    // 32 KB
    int* stok   = (int*)(ws + 75563008);                      // 32 KB
    int* list   = (int*)(ws + 75595776);                      // 128 KB
    int* cnt    = (int*)(ws + 75726848);                      // 64 B
    float* pprob= (float*)(ws + 75726976);                    // 8 KB

    float* outlb = out + (size_t)NTOK * H;
    hipMemsetAsync(cnt, 0, 8 * sizeof(int), stream);
    hipMemsetAsync(outlb, 0, sizeof(float), stream);
    transpose_cvt_kernel<<<4096, 256, 0, stream>>>(W1, w1t, W2, w2t);
    router_kernel<<<256, 256, 0, stream>>>(x, Wg, gate, list, cnt, pprob);
    gather_kernel<<<2048, 256, 0, stream>>>(x, gate, list, cnt, pprob, xg, gs, stok, outlb);
    gemm1_kernel<<<1024, 512, 0, stream>>>(xg, w1t, b1, cnt, hbf);
    gemm2_kernel<<<1024, 256, 0, stream>>>(hbf, w2t, b2, cnt, gs, stok, out);
}

// Round 9
// 119.304 us; speedup vs baseline: 1.3090x; 1.1580x over previous
//
#include <hip/hip_runtime.h>
#include <hip/hip_bf16.h>
#include <stdint.h>

#define H 512
#define F 2048
#define E 8
#define NTOK 8192
#define LSTRIDE 4096

typedef __bf16 bf16x8 __attribute__((ext_vector_type(8)));
typedef float f32x4 __attribute__((ext_vector_type(4)));

__device__ __forceinline__ unsigned short f2bf(float f) {
    unsigned u = __builtin_bit_cast(unsigned, f);
    u += 0x7FFFu + ((u >> 16) & 1u);
    return (unsigned short)(u >> 16);
}

__device__ __forceinline__ void gl_lds16(const unsigned short* g, unsigned short* l) {
    __builtin_amdgcn_global_load_lds(
        (const __attribute__((address_space(1))) unsigned int*)g,
        (__attribute__((address_space(3))) unsigned int*)l,
        16, 0, 0);
}

// ---------- fused prep: blocks [0,4096) transpose+cvt W1/W2, [4096,4352) router ----------
__global__ void prep_kernel(const float* __restrict__ W1, unsigned short* __restrict__ w1t,
                            const float* __restrict__ W2, unsigned short* __restrict__ w2t,
                            const float* __restrict__ x, const float* __restrict__ Wg,
                            float* __restrict__ gate, int* __restrict__ list,
                            int* __restrict__ cnt, float* __restrict__ pprob) {
    __shared__ unsigned short t[64][72];
    __shared__ float wg[H * E];
    __shared__ float lg[32][8];
    __shared__ int am_l[32];
    __shared__ int rank_l[32];
    __shared__ int eb[8];
    int tid = threadIdx.x;

    if (blockIdx.x < 4096) {
        // ---- transpose+cvt ----
        int id = blockIdx.x;
        const float* src; unsigned short* dst; int R, C, r0, c0;
        if (id < 2048) {
            R = 512; C = 2048;
            int z = id >> 8, y = (id >> 5) & 7, xx = id & 31;
            src = W1 + (size_t)z * R * C; dst = w1t + (size_t)z * R * C;
            r0 = y * 64; c0 = xx * 64;
        } else {
            int id2 = id - 2048;
            R = 2048; C = 512;
            int z = id2 >> 8, y = id2 & 31, xx = (id2 >> 5) & 7;
            src = W2 + (size_t)z * R * C; dst = w2t + (size_t)z * R * C;
            r0 = y * 64; c0 = xx * 64;
        }
        int lrow = tid >> 4, lc4 = (tid & 15) * 4;
        #pragma unroll
        for (int p = 0; p < 4; ++p) {
            int r = p * 16 + lrow;
            float4 v = *(const float4*)(src + (size_t)(r0 + r) * C + c0 + lc4);
            uint2 u;
            u.x = (unsigned)f2bf(v.x) | ((unsigned)f2bf(v.y) << 16);
            u.y = (unsigned)f2bf(v.z) | ((unsigned)f2bf(v.w) << 16);
            *(uint2*)(&t[r][lc4]) = u;
        }
        __syncthreads();
        int och = tid & 7;
        #pragma unroll
        for (int q = 0; q < 2; ++q) {
            int orow = q * 32 + (tid >> 3);
            unsigned short u[8];
            #pragma unroll
            for (int si = 0; si < 8; ++si) u[si] = t[och * 8 + si][orow];
            uint4 uv;
            uv.x = (unsigned)u[0] | ((unsigned)u[1] << 16);
            uv.y = (unsigned)u[2] | ((unsigned)u[3] << 16);
            uv.z = (unsigned)u[4] | ((unsigned)u[5] << 16);
            uv.w = (unsigned)u[6] | ((unsigned)u[7] << 16);
            *(uint4*)(dst + (size_t)(c0 + orow) * R + r0 + och * 8) = uv;
        }
        return;
    }

    // ---- router ----
    int rbid = blockIdx.x - 4096;
    #pragma unroll
    for (int p = 0; p < 16; ++p) wg[p * 256 + tid] = Wg[p * 256 + tid];
    __syncthreads();

    int tl = tid >> 3, e = tid & 7;
    int token = rbid * 32 + tl;
    const float4* x4 = (const float4*)(x + (size_t)token * H);
    float acc = 0.f;
    for (int kq = 0; kq < 128; ++kq) {
        float4 v = x4[kq];
        acc += v.x * wg[(kq * 4 + 0) * 8 + e];
        acc += v.y * wg[(kq * 4 + 1) * 8 + e];
        acc += v.z * wg[(kq * 4 + 2) * 8 + e];
        acc += v.w * wg[(kq * 4 + 3) * 8 + e];
    }
    lg[tl][e] = acc;
    __syncthreads();

    if (tid < 32) {
        float l[8];
        #pragma unroll
        for (int q = 0; q < 8; ++q) l[q] = lg[tid][q];
        float mx = l[0];
        #pragma unroll
        for (int q = 1; q < 8; ++q) mx = fmaxf(mx, l[q]);
        float p[8]; float s = 0.f;
        #pragma unroll
        for (int q = 0; q < 8; ++q) { p[q] = expf(l[q] - mx); s += p[q]; }
        int am = 0; float best = l[0];
        #pragma unroll
        for (int q = 1; q < 8; ++q) if (l[q] > best) { best = l[q]; am = q; }
        float inv = 1.f / s;
        #pragma unroll
        for (int q = 0; q < 8; ++q) lg[tid][q] = p[q] * inv;
        float sp = p[am] * inv;
        gate[rbid * 32 + tid] = sp / (sp + 1e-8f);
        am_l[tid] = am;
    }
    __syncthreads();

    if (tid < 8) {
        float s = 0.f;
        for (int i = 0; i < 32; ++i) s += lg[i][tid];
        pprob[rbid * 8 + tid] = s;
        int c = 0;
        for (int i = 0; i < 32; ++i) if (am_l[i] == tid) rank_l[i] = c++;
        eb[tid] = atomicAdd(&cnt[tid], c);
    }
    __syncthreads();

    if (tid < 32) {
        int e2 = am_l[tid];
        int pos = eb[e2] + rank_l[tid];
        if (pos < LSTRIDE) list[e2 * LSTRIDE + pos] = rbid * 32 + tid;
    }
}

__device__ __forceinline__ void load_ebase(const int* __restrict__ cnt, int* eb) {
    int b = 0;
    #pragma unroll
    for (int q = 0; q < 8; ++q) { eb[q] = b; b += cnt[q]; }
}

// ---------- gather: x -> xg (bf16, expert-sorted) + gs/stok; block 0 computes lb ----------
__global__ void gather_kernel(const float* __restrict__ x, const float* __restrict__ gate,
                              const int* __restrict__ list, const int* __restrict__ cnt,
                              const float* __restrict__ pprob,
                              unsigned short* __restrict__ xg, float* __restrict__ gs,
                              int* __restrict__ stok, float* __restrict__ outlb) {
    __shared__ float lbp[8];
    int eb[8];
    load_ebase(cnt, eb);
    if (blockIdx.x == 0) {
        if (threadIdx.x < 8) {
            int t = threadIdx.x;
            float acc = 0.f;
            for (int i = 0; i < 256; ++i) acc += pprob[i * 8 + t];
            lbp[t] = acc * (float)cnt[t];
        }
        __syncthreads();
        if (threadIdx.x == 0) {
            float tot = 0.f;
            #pragma unroll
            for (int q = 0; q < 8; ++q) tot += lbp[q];
            outlb[0] = tot * (8.0f / ((float)NTOK * (float)NTOK));
        }
    }
    int p = blockIdx.x * 4 + (threadIdx.x >> 6);
    int lane = threadIdx.x & 63;
    int e = 0;
    #pragma unroll
    for (int q = 1; q < 8; ++q) if (p >= eb[q]) e = q;
    int token = list[e * LSTRIDE + (p - eb[e])];
    const float4* src = (const float4*)(x + (size_t)token * H) + lane * 2;
    float4 a = src[0], b = src[1];
    uint4 u;
    u.x = (unsigned)f2bf(a.x) | ((unsigned)f2bf(a.y) << 16);
    u.y = (unsigned)f2bf(a.z) | ((unsigned)f2bf(a.w) << 16);
    u.z = (unsigned)f2bf(b.x) | ((unsigned)f2bf(b.y) << 16);
    u.w = (unsigned)f2bf(b.z) | ((unsigned)f2bf(b.w) << 16);
    *(uint4*)(xg + (size_t)p * H + lane * 8) = u;
    if (lane == 0) { stok[p] = token; gs[p] = gate[token]; }
}

// ---------- GEMM1: h = relu(xg @ W1t^T + b1), 128x128xBK64, counted-vmcnt(8) dbuf (R6 best) ----------
__global__ __launch_bounds__(256, 2) void gemm1_kernel(
    const unsigned short* __restrict__ xg,    // [NTOK][H] sorted
    const unsigned short* __restrict__ w1t,   // [E][F][H]
    const float* __restrict__ b1,
    const int* __restrict__ cnt,
    unsigned short* __restrict__ hbf)         // [NTOK][F] sorted
{
    int bid = blockIdx.x;
    int e = bid & 7;                 // expert -> XCD
    int idx = bid >> 3;              // 0..511
    int mblk = idx >> 4;             // 0..31, m-major
    int c = cnt[e];
    if (mblk * 128 >= c) return;
    int n0 = (idx & 15) * 128;       // n fastest -> same-XCD A-tile reuse
    int eb[8]; load_ebase(cnt, eb);
    int m0 = eb[e] + mblk * 128;
    int segEnd = eb[e] + c;

    __shared__ unsigned short Al[2][128 * 64];   // 2 x 16 KB
    __shared__ unsigned short Bl[2][128 * 64];   // 2 x 16 KB

    int tid = threadIdx.x, lane = tid & 63, w = tid >> 6;
    int lr8 = lane >> 3, lch = lane & 7;
    int swc = lch ^ lr8;                       // source-side chunk swizzle

    const unsigned short* asrc[4];
    const unsigned short* bsrc[4];
    #pragma unroll
    for (int i = 0; i < 4; ++i) {
        int seg = w * 4 + i;
        int row = seg * 8 + lr8;
        int ar = m0 + row; if (ar > NTOK - 1) ar = NTOK - 1;
        asrc[i] = xg + (size_t)ar * H + swc * 8;
        bsrc[i] = w1t + ((size_t)e * F + n0 + row) * H + swc * 8;
    }

    f32x4 acc[4][4] = {};
    int mb = (w >> 1) * 64, nb = (w & 1) * 64;
    int lr = lane & 15, x16 = lane >> 4;
    int sw = (lr & 7) << 4;                    // read-side byte XOR

    // prologue: stage tile 0 into buf 0 (8 loads/thread in flight)
    #pragma unroll
    for (int i = 0; i < 4; ++i) {
        gl_lds16(asrc[i], &Al[0][(w * 4 + i) * 512]);
        gl_lds16(bsrc[i], &Bl[0][(w * 4 + i) * 512]);
    }

    int cur = 0;
    #pragma unroll
    for (int t = 0; t < 8; ++t) {
        if (t < 7) {
            int k0 = (t + 1) * 64;
            #pragma unroll
            for (int i = 0; i < 4; ++i) {
                gl_lds16(asrc[i] + k0, &Al[cur ^ 1][(w * 4 + i) * 512]);
                gl_lds16(bsrc[i] + k0, &Bl[cur ^ 1][(w * 4 + i) * 512]);
            }
            asm volatile("s_waitcnt vmcnt(8)" ::: "memory");  // tile t landed; t+1 in flight
        } else {
            asm volatile("s_waitcnt vmcnt(0)" ::: "memory");
        }
        __builtin_amdgcn_s_barrier();          // all waves' tile-t loads visible
        #pragma unroll
        for (int kk = 0; kk < 2; ++kk) {
            int co = (kk * 64 + x16 * 16) ^ sw;
            bf16x8 a[4], b[4];
            #pragma unroll
            for (int i = 0; i < 4; ++i)
                a[i] = *(const bf16x8*)((const char*)Al[cur] + (mb + i * 16 + lr) * 128 + co);
            #pragma unroll
            for (int j = 0; j < 4; ++j)
                b[j] = *(const bf16x8*)((const char*)Bl[cur] + (nb + j * 16 + lr) * 128 + co);
            #pragma unroll
            for (int i = 0; i < 4; ++i)
                #pragma unroll
                for (int j = 0; j < 4; ++j)
                    acc[i][j] = __builtin_amdgcn_mfma_f32_16x16x32_bf16(b[j], a[i], acc[i][j], 0, 0, 0);
        }
        asm volatile("s_waitcnt lgkmcnt(0)" ::: "memory");    // done reading buf[cur]
        __builtin_amdgcn_s_barrier();          // before next iter overwrites it
        cur ^= 1;
    }

    // epilogue: lane holds 4 consecutive F-cols of one token -> 8B packed stores
    int w4 = x16 * 4;
    #pragma unroll
    for (int j = 0; j < 4; ++j) {
        int gc = n0 + nb + j * 16 + w4;
        float4 bias = *(const float4*)(b1 + e * F + gc);
        #pragma unroll
        for (int i = 0; i < 4; ++i) {
            int p = m0 + mb + i * 16 + lr;
            if (p < segEnd) {
                float v0 = acc[i][j][0] + bias.x; v0 = v0 > 0.f ? v0 : 0.f;
                float v1 = acc[i][j][1] + bias.y; v1 = v1 > 0.f ? v1 : 0.f;
                float v2 = acc[i][j][2] + bias.z; v2 = v2 > 0.f ? v2 : 0.f;
                float v3 = acc[i][j][3] + bias.w; v3 = v3 > 0.f ? v3 : 0.f;
                uint2 pk;
                pk.x = (unsigned)f2bf(v0) | ((unsigned)f2bf(v1) << 16);
                pk.y = (unsigned)f2bf(v2) | ((unsigned)f2bf(v3) << 16);
                *(uint2*)(hbf + (size_t)p * F + gc) = pk;
            }
        }
    }
}

// ---------- GEMM2: out = gate*(h @ W2t^T + b2) scattered, 128x128xBK64, counted-vmcnt(8) dbuf ----------
__global__ __launch_bounds__(256, 2) void gemm2_kernel(
    const unsigned short* __restrict__ hbf,   // [NTOK][F] sorted
    const unsigned short* __restrict__ w2t,   // [E][H][F]
    const float* __restrict__ b2,
    const int* __restrict__ cnt,
    const float* __restrict__ gs, const int* __restrict__ stok,
    float* __restrict__ out)                  // [NTOK][H] token order
{
    int bid = blockIdx.x;
    int e = bid & 7;
    int idx = bid >> 3;              // 0..127
    int mblk = idx >> 2;             // 0..31
    int c = cnt[e];
    if (mblk * 128 >= c) return;
    int n0 = (idx & 3) * 128;
    int eb[8]; load_ebase(cnt, eb);
    int m0 = eb[e] + mblk * 128;
    int segEnd = eb[e] + c;

    __shared__ unsigned short Al[2][128 * 64];   // 2 x 16 KB
    __shared__ unsigned short Bl[2][128 * 64];   // 2 x 16 KB
    __shared__ int stokL[128];
    __shared__ float gsL[128];

    int tid = threadIdx.x, lane = tid & 63, w = tid >> 6;
    if (tid < 128) {
        int p = m0 + tid;
        int pc = p > NTOK - 1 ? NTOK - 1 : p;
        stokL[tid] = stok[pc];
        gsL[tid] = gs[pc];
    }
    int lr8 = lane >> 3, lch = lane & 7;
    int swc = lch ^ lr8;

    const unsigned short* asrc[4];
    const unsigned short* bsrc[4];
    #pragma unroll
    for (int i = 0; i < 4; ++i) {
        int row = (w * 4 + i) * 8 + lr8;
        int ar = m0 + row; if (ar > NTOK - 1) ar = NTOK - 1;
        asrc[i] = hbf + (size_t)ar * F + swc * 8;
        bsrc[i] = w2t + ((size_t)e * H + n0 + row) * F + swc * 8;
    }

    f32x4 acc[4][4] = {};
    int mb = (w >> 1) * 64, nb = (w & 1) * 64;
    int lr = lane & 15, x16 = lane >> 4;
    int sw = (lr & 7) << 4;

    // prologue
    #pragma unroll
    for (int i = 0; i < 4; ++i) {
        gl_lds16(asrc[i], &Al[0][(w * 4 + i) * 512]);
        gl_lds16(bsrc[i], &Bl[0][(w * 4 + i) * 512]);
    }
    __builtin_amdgcn_s_barrier();   // stokL/gsL visibility

    int cur = 0;
    #pragma unroll
    for (int t = 0; t < 32; ++t) {
        if (t < 31) {
            int k0 = (t + 1) * 64;
            #pragma unroll
            for (int i = 0; i < 4; ++i) {
                gl_lds16(asrc[i] + k0, &Al[cur ^ 1][(w * 4 + i) * 512]);
                gl_lds16(bsrc[i] + k0, &Bl[cur ^ 1][(w * 4 + i) * 512]);
            }
            asm volatile("s_waitcnt vmcnt(8)" ::: "memory");
        } else {
            asm volatile("s_waitcnt vmcnt(0)" ::: "memory");
        }
        __builtin_amdgcn_s_barrier();
        #pragma unroll
        for (int kk = 0; kk < 2; ++kk) {
            int co = (kk * 64 + x16 * 16) ^ sw;
            bf16x8 a[4], b[4];
            #pragma unroll
            for (int i = 0; i < 4; ++i)
                a[i] = *(const bf16x8*)((const char*)Al[cur] + (mb + i * 16 + lr) * 128 + co);
            #pragma unroll
            for (int j = 0; j < 4; ++j)
                b[j] = *(const bf16x8*)((const char*)Bl[cur] + (nb + j * 16 + lr) * 128 + co);
            #pragma unroll
            for (int i = 0; i < 4; ++i)
                #pragma unroll
                for (int j = 0; j < 4; ++j)
                    acc[i][j] = __builtin_amdgcn_mfma_f32_16x16x32_bf16(b[j], a[i], acc[i][j], 0, 0, 0);
        }
        asm volatile("s_waitcnt lgkmcnt(0)" ::: "memory");
        __builtin_amdgcn_s_barrier();
        cur ^= 1;
    }

    // epilogue: lane holds 4 consecutive H-cols of one token -> float4 stores
    int w4 = x16 * 4;
    #pragma unroll
    for (int i = 0; i < 4; ++i) {
        int rl = mb + i * 16 + lr;
        int p = m0 + rl;
        if (p < segEnd) {
            int tok = stokL[rl];
            float g = gsL[rl];
            #pragma unroll
            for (int j = 0; j < 4; ++j) {
                int gc = n0 + nb + j * 16 + w4;
                float4 bias = *(const float4*)(b2 + e * H + gc);
                float4 res;
                res.x = g * (acc[i][j][0] + bias.x);
                res.y = g * (acc[i][j][1] + bias.y);
                res.z = g * (acc[i][j][2] + bias.z);
                res.w = g * (acc[i][j][3] + bias.w);
                *(float4*)(out + (size_t)tok * H + gc) = res;
            }
        }
    }
}

extern "C" void kernel_launch(void* const* d_in, const int* in_sizes, int n_in,
                              void* d_out, int out_size, void* d_ws, size_t ws_size,
                              hipStream_t stream) {
    const float* x  = (const float*)d_in[0];
    const float* Wg = (const float*)d_in[1];
    const float* W1 = (const float*)d_in[2];
    const float* b1 = (const float*)d_in[3];
    const float* W2 = (const float*)d_in[4];
    const float* b2 = (const float*)d_in[5];
    float* out = (float*)d_out;

    char* ws = (char*)d_ws;
    unsigned short* xg  = (unsigned short*)(ws + 0);          //  8 MB
    unsigned short* w1t = (unsigned short*)(ws + 8388608);    // 16 MB
    unsigned short* w2t = (unsigned short*)(ws + 25165824);   // 16 MB
    unsigned short* hbf = (unsigned short*)(ws + 41943040);   // 32 MB
    float* gate = (float*)(ws + 75497472);                    // 32 KB
    float* gs   = (float*)(ws + 75530240);                    // 32 KB
    int* stok   = (int*)(ws + 75563008);                      // 32 KB
    int* list   = (int*)(ws + 75595776);                      // 128 KB
    int* cnt    = (int*)(ws + 75726848);                      // 64 B
    float* pprob= (float*)(ws + 75726976);                    // 8 KB

    float* outlb = out + (size_t)NTOK * H;
    hipMemsetAsync(cnt, 0, 8 * sizeof(int), stream);
    prep_kernel<<<4352, 256, 0, stream>>>(W1, w1t, W2, w2t, x, Wg, gate, list, cnt, pprob);
    gather_kernel<<<2048, 256, 0, stream>>>(x, gate, list, cnt, pprob, xg, gs, stok, outlb);
    gemm1_kernel<<<4096, 256, 0, stream>>>(xg, w1t, b1, cnt, hbf);
    gemm2_kernel<<<1024, 256, 0, stream>>>(hbf, w2t, b2, cnt, gs, stok, out);
}

// Round 10
// 112.815 us; speedup vs baseline: 1.3843x; 1.0575x over previous
//
#include <hip/hip_runtime.h>
#include <hip/hip_bf16.h>
#include <stdint.h>

#define H 512
#define F 2048
#define E 8
#define NTOK 8192
#define LSTRIDE 4096

typedef __bf16 bf16x8 __attribute__((ext_vector_type(8)));
typedef float f32x4 __attribute__((ext_vector_type(4)));

__device__ __forceinline__ unsigned short f2bf(float f) {
    unsigned u = __builtin_bit_cast(unsigned, f);
    u += 0x7FFFu + ((u >> 16) & 1u);
    return (unsigned short)(u >> 16);
}

__device__ __forceinline__ void gl_lds16(const unsigned short* g, unsigned short* l) {
    __builtin_amdgcn_global_load_lds(
        (const __attribute__((address_space(1))) unsigned int*)g,
        (__attribute__((address_space(3))) unsigned int*)l,
        16, 0, 0);
}

// ---------- fused prep: blocks [0,4096) LDS-free transpose+cvt W1/W2, [4096,4352) router ----------
__global__ void prep_kernel(const float* __restrict__ W1, unsigned short* __restrict__ w1t,
                            const float* __restrict__ W2, unsigned short* __restrict__ w2t,
                            const float* __restrict__ x, const float* __restrict__ Wg,
                            float* __restrict__ gate, int* __restrict__ list,
                            int* __restrict__ cnt, float* __restrict__ pprob) {
    __shared__ float wg[H * E];        // router path only (16 KB)
    __shared__ float lg[32][8];
    __shared__ int am_l[32];
    __shared__ int rank_l[32];
    __shared__ int eb[8];
    int tid = threadIdx.x;

    if (blockIdx.x < 4096) {
        // ---- register transpose: src [R][C] fp32 -> dst [C][R] bf16 (64x64 tile) ----
        int id = blockIdx.x;
        const float* src; unsigned short* dst; int R, C, r0, c0;
        if (id < 2048) {
            R = 512; C = 2048;
            int z = id >> 8;
            src = W1 + (size_t)z * R * C; dst = w1t + (size_t)z * R * C;
            r0 = ((id >> 5) & 7) * 64; c0 = (id & 31) * 64;
        } else {
            int id2 = id - 2048;
            R = 2048; C = 512;
            int z = id2 >> 8;
            src = W2 + (size_t)z * R * C; dst = w2t + (size_t)z * R * C;
            r0 = (id2 & 31) * 64; c0 = ((id2 >> 5) & 7) * 64;
        }
        int c = tid & 63, rcg = tid >> 6;
        const float* sp = src + (size_t)c0 + c;
        unsigned short* dp = dst + (size_t)(c0 + c) * R + r0;
        #pragma unroll
        for (int h = 0; h < 2; ++h) {
            int rc = rcg + h * 4;
            int rb = r0 + rc * 8;
            unsigned us[8];
            #pragma unroll
            for (int k = 0; k < 8; ++k)
                us[k] = f2bf(sp[(size_t)(rb + k) * C]);   // lane-coalesced (c consecutive)
            uint4 uv;
            uv.x = us[0] | (us[1] << 16);
            uv.y = us[2] | (us[3] << 16);
            uv.z = us[4] | (us[5] << 16);
            uv.w = us[6] | (us[7] << 16);
            *(uint4*)(dp + rc * 8) = uv;                  // 16B packed store
        }
        return;
    }

    // ---- router ----
    int rbid = blockIdx.x - 4096;
    #pragma unroll
    for (int p = 0; p < 16; ++p) wg[p * 256 + tid] = Wg[p * 256 + tid];
    __syncthreads();

    int tl = tid >> 3, e = tid & 7;
    int token = rbid * 32 + tl;
    const float4* x4 = (const float4*)(x + (size_t)token * H);
    float acc = 0.f;
    for (int kq = 0; kq < 128; ++kq) {
        float4 v = x4[kq];
        acc += v.x * wg[(kq * 4 + 0) * 8 + e];
        acc += v.y * wg[(kq * 4 + 1) * 8 + e];
        acc += v.z * wg[(kq * 4 + 2) * 8 + e];
        acc += v.w * wg[(kq * 4 + 3) * 8 + e];
    }
    lg[tl][e] = acc;
    __syncthreads();

    if (tid < 32) {
        float l[8];
        #pragma unroll
        for (int q = 0; q < 8; ++q) l[q] = lg[tid][q];
        float mx = l[0];
        #pragma unroll
        for (int q = 1; q < 8; ++q) mx = fmaxf(mx, l[q]);
        float p[8]; float s = 0.f;
        #pragma unroll
        for (int q = 0; q < 8; ++q) { p[q] = expf(l[q] - mx); s += p[q]; }
        int am = 0; float best = l[0];
        #pragma unroll
        for (int q = 1; q < 8; ++q) if (l[q] > best) { best = l[q]; am = q; }
        float inv = 1.f / s;
        #pragma unroll
        for (int q = 0; q < 8; ++q) lg[tid][q] = p[q] * inv;
        float sp = p[am] * inv;
        gate[rbid * 32 + tid] = sp / (sp + 1e-8f);
        am_l[tid] = am;
    }
    __syncthreads();

    if (tid < 8) {
        float s = 0.f;
        for (int i = 0; i < 32; ++i) s += lg[i][tid];
        pprob[rbid * 8 + tid] = s;
        int c = 0;
        for (int i = 0; i < 32; ++i) if (am_l[i] == tid) rank_l[i] = c++;
        eb[tid] = atomicAdd(&cnt[tid], c);
    }
    __syncthreads();

    if (tid < 32) {
        int e2 = am_l[tid];
        int pos = eb[e2] + rank_l[tid];
        if (pos < LSTRIDE) list[e2 * LSTRIDE + pos] = rbid * 32 + tid;
    }
}

__device__ __forceinline__ void load_ebase(const int* __restrict__ cnt, int* eb) {
    int b = 0;
    #pragma unroll
    for (int q = 0; q < 8; ++q) { eb[q] = b; b += cnt[q]; }
}

// ---------- gather: x -> xg (bf16, expert-sorted) + gs/stok; block 0 computes lb ----------
__global__ void gather_kernel(const float* __restrict__ x, const float* __restrict__ gate,
                              const int* __restrict__ list, const int* __restrict__ cnt,
                              const float* __restrict__ pprob,
                              unsigned short* __restrict__ xg, float* __restrict__ gs,
                              int* __restrict__ stok, float* __restrict__ outlb) {
    __shared__ float lbp[8];
    int eb[8];
    load_ebase(cnt, eb);
    if (blockIdx.x == 0) {
        if (threadIdx.x < 8) {
            int t = threadIdx.x;
            float acc = 0.f;
            for (int i = 0; i < 256; ++i) acc += pprob[i * 8 + t];
            lbp[t] = acc * (float)cnt[t];
        }
        __syncthreads();
        if (threadIdx.x == 0) {
            float tot = 0.f;
            #pragma unroll
            for (int q = 0; q < 8; ++q) tot += lbp[q];
            outlb[0] = tot * (8.0f / ((float)NTOK * (float)NTOK));
        }
    }
    int p = blockIdx.x * 4 + (threadIdx.x >> 6);
    int lane = threadIdx.x & 63;
    int e = 0;
    #pragma unroll
    for (int q = 1; q < 8; ++q) if (p >= eb[q]) e = q;
    int token = list[e * LSTRIDE + (p - eb[e])];
    const float4* src = (const float4*)(x + (size_t)token * H) + lane * 2;
    float4 a = src[0], b = src[1];
    uint4 u;
    u.x = (unsigned)f2bf(a.x) | ((unsigned)f2bf(a.y) << 16);
    u.y = (unsigned)f2bf(a.z) | ((unsigned)f2bf(a.w) << 16);
    u.z = (unsigned)f2bf(b.x) | ((unsigned)f2bf(b.y) << 16);
    u.w = (unsigned)f2bf(b.z) | ((unsigned)f2bf(b.w) << 16);
    *(uint4*)(xg + (size_t)p * H + lane * 8) = u;
    if (lane == 0) { stok[p] = token; gs[p] = gate[token]; }
}

// ---------- GEMM1: h = relu(xg @ W1t^T + b1), 128x128xBK64, counted-vmcnt(8) dbuf ----------
__global__ __launch_bounds__(256, 2) void gemm1_kernel(
    const unsigned short* __restrict__ xg,    // [NTOK][H] sorted
    const unsigned short* __restrict__ w1t,   // [E][F][H]
    const float* __restrict__ b1,
    const int* __restrict__ cnt,
    unsigned short* __restrict__ hbf)         // [NTOK][F] sorted
{
    int bid = blockIdx.x;
    int e = bid & 7;                 // expert -> XCD
    int idx = bid >> 3;              // 0..511
    int mblk = idx >> 4;             // 0..31, m-major
    int c = cnt[e];
    if (mblk * 128 >= c) return;
    int n0 = (idx & 15) * 128;       // n fastest -> same-XCD A-tile reuse
    int eb[8]; load_ebase(cnt, eb);
    int m0 = eb[e] + mblk * 128;
    int segEnd = eb[e] + c;

    __shared__ unsigned short Al[2][128 * 64];   // 2 x 16 KB
    __shared__ unsigned short Bl[2][128 * 64];   // 2 x 16 KB

    int tid = threadIdx.x, lane = tid & 63, w = tid >> 6;
    int lr8 = lane >> 3, lch = lane & 7;
    int swc = lch ^ lr8;                       // source-side chunk swizzle

    const unsigned short* asrc[4];
    const unsigned short* bsrc[4];
    #pragma unroll
    for (int i = 0; i < 4; ++i) {
        int seg = w * 4 + i;
        int row = seg * 8 + lr8;
        int ar = m0 + row; if (ar > NTOK - 1) ar = NTOK - 1;
        asrc[i] = xg + (size_t)ar * H + swc * 8;
        bsrc[i] = w1t + ((size_t)e * F + n0 + row) * H + swc * 8;
    }

    f32x4 acc[4][4] = {};
    int mb = (w >> 1) * 64, nb = (w & 1) * 64;
    int lr = lane & 15, x16 = lane >> 4;
    int sw = (lr & 7) << 4;                    // read-side byte XOR

    // prologue: stage tile 0 into buf 0 (8 loads/thread in flight)
    #pragma unroll
    for (int i = 0; i < 4; ++i) {
        gl_lds16(asrc[i], &Al[0][(w * 4 + i) * 512]);
        gl_lds16(bsrc[i], &Bl[0][(w * 4 + i) * 512]);
    }

    int cur = 0;
    #pragma unroll
    for (int t = 0; t < 8; ++t) {
        if (t < 7) {
            int k0 = (t + 1) * 64;
            #pragma unroll
            for (int i = 0; i < 4; ++i) {
                gl_lds16(asrc[i] + k0, &Al[cur ^ 1][(w * 4 + i) * 512]);
                gl_lds16(bsrc[i] + k0, &Bl[cur ^ 1][(w * 4 + i) * 512]);
            }
            asm volatile("s_waitcnt vmcnt(8)" ::: "memory");  // tile t landed; t+1 in flight
        } else {
            asm volatile("s_waitcnt vmcnt(0)" ::: "memory");
        }
        __builtin_amdgcn_s_barrier();          // all waves' tile-t loads visible
        #pragma unroll
        for (int kk = 0; kk < 2; ++kk) {
            int co = (kk * 64 + x16 * 16) ^ sw;
            bf16x8 a[4], b[4];
            #pragma unroll
            for (int i = 0; i < 4; ++i)
                a[i] = *(const bf16x8*)((const char*)Al[cur] + (mb + i * 16 + lr) * 128 + co);
            #pragma unroll
            for (int j = 0; j < 4; ++j)
                b[j] = *(const bf16x8*)((const char*)Bl[cur] + (nb + j * 16 + lr) * 128 + co);
            #pragma unroll
            for (int i = 0; i < 4; ++i)
                #pragma unroll
                for (int j = 0; j < 4; ++j)
                    acc[i][j] = __builtin_amdgcn_mfma_f32_16x16x32_bf16(b[j], a[i], acc[i][j], 0, 0, 0);
        }
        asm volatile("s_waitcnt lgkmcnt(0)" ::: "memory");    // done reading buf[cur]
        __builtin_amdgcn_s_barrier();          // before next iter overwrites it
        cur ^= 1;
    }

    // epilogue: lane holds 4 consecutive F-cols of one token -> 8B packed stores
    int w4 = x16 * 4;
    #pragma unroll
    for (int j = 0; j < 4; ++j) {
        int gc = n0 + nb + j * 16 + w4;
        float4 bias = *(const float4*)(b1 + e * F + gc);
        #pragma unroll
        for (int i = 0; i < 4; ++i) {
            int p = m0 + mb + i * 16 + lr;
            if (p < segEnd) {
                float v0 = acc[i][j][0] + bias.x; v0 = v0 > 0.f ? v0 : 0.f;
                float v1 = acc[i][j][1] + bias.y; v1 = v1 > 0.f ? v1 : 0.f;
                float v2 = acc[i][j][2] + bias.z; v2 = v2 > 0.f ? v2 : 0.f;
                float v3 = acc[i][j][3] + bias.w; v3 = v3 > 0.f ? v3 : 0.f;
                uint2 pk;
                pk.x = (unsigned)f2bf(v0) | ((unsigned)f2bf(v1) << 16);
                pk.y = (unsigned)f2bf(v2) | ((unsigned)f2bf(v3) << 16);
                *(uint2*)(hbf + (size_t)p * F + gc) = pk;
            }
        }
    }
}

// ---------- GEMM2: out = gate*(h @ W2t^T + b2) scattered, 64x128xBK64, counted-vmcnt(6), 3/CU ----------
__global__ __launch_bounds__(256, 3) void gemm2_kernel(
    const unsigned short* __restrict__ hbf,   // [NTOK][F] sorted
    const unsigned short* __restrict__ w2t,   // [E][H][F]
    const float* __restrict__ b2,
    const int* __restrict__ cnt,
    const float* __restrict__ gs, const int* __restrict__ stok,
    float* __restrict__ out)                  // [NTOK][H] token order
{
    int bid = blockIdx.x;
    int e = bid & 7;
    int idx = bid >> 3;              // 0..255
    int mblk = idx >> 2;             // 0..63
    int c = cnt[e];
    if (mblk * 64 >= c) return;
    int n0 = (idx & 3) * 128;
    int eb[8]; load_ebase(cnt, eb);
    int m0 = eb[e] + mblk * 64;
    int segEnd = eb[e] + c;

    __shared__ unsigned short Al[2][64 * 64];    // 2 x 8 KB
    __shared__ unsigned short Bl[2][128 * 64];   // 2 x 16 KB
    __shared__ int stokL[64];
    __shared__ float gsL[64];

    int tid = threadIdx.x, lane = tid & 63, w = tid >> 6;
    if (tid < 64) {
        int p = m0 + tid;
        int pc = p > NTOK - 1 ? NTOK - 1 : p;
        stokL[tid] = stok[pc];
        gsL[tid] = gs[pc];
    }
    int lr8 = lane >> 3, lch = lane & 7;
    int swc = lch ^ lr8;

    const unsigned short* asrc[2];
    const unsigned short* bsrc[4];
    #pragma unroll
    for (int i = 0; i < 2; ++i) {
        int row = (w * 2 + i) * 8 + lr8;
        int ar = m0 + row; if (ar > NTOK - 1) ar = NTOK - 1;
        asrc[i] = hbf + (size_t)ar * F + swc * 8;
    }
    #pragma unroll
    for (int i = 0; i < 4; ++i) {
        int row = (w * 4 + i) * 8 + lr8;
        bsrc[i] = w2t + ((size_t)e * H + n0 + row) * F + swc * 8;
    }

    f32x4 acc[2][4] = {};
    int mb = (w >> 1) * 32, nb = (w & 1) * 64;
    int lr = lane & 15, x16 = lane >> 4;
    int sw = (lr & 7) << 4;

    // prologue: 6 loads/thread
    #pragma unroll
    for (int i = 0; i < 2; ++i) gl_lds16(asrc[i], &Al[0][(w * 2 + i) * 512]);
    #pragma unroll
    for (int i = 0; i < 4; ++i) gl_lds16(bsrc[i], &Bl[0][(w * 4 + i) * 512]);
    __builtin_amdgcn_s_barrier();   // stokL/gsL visibility

    int cur = 0;
    #pragma unroll
    for (int t = 0; t < 32; ++t) {
        if (t < 31) {
            int k0 = (t + 1) * 64;
            #pragma unroll
            for (int i = 0; i < 2; ++i) gl_lds16(asrc[i] + k0, &Al[cur ^ 1][(w * 2 + i) * 512]);
            #pragma unroll
            for (int i = 0; i < 4; ++i) gl_lds16(bsrc[i] + k0, &Bl[cur ^ 1][(w * 4 + i) * 512]);
            asm volatile("s_waitcnt vmcnt(6)" ::: "memory");   // tile t landed; t+1 in flight
        } else {
            asm volatile("s_waitcnt vmcnt(0)" ::: "memory");
        }
        __builtin_amdgcn_s_barrier();
        #pragma unroll
        for (int kk = 0; kk < 2; ++kk) {
            int co = (kk * 64 + x16 * 16) ^ sw;
            bf16x8 a[2], b[4];
            #pragma unroll
            for (int i = 0; i < 2; ++i)
                a[i] = *(const bf16x8*)((const char*)Al[cur] + (mb + i * 16 + lr) * 128 + co);
            #pragma unroll
            for (int j = 0; j < 4; ++j)
                b[j] = *(const bf16x8*)((const char*)Bl[cur] + (nb + j * 16 + lr) * 128 + co);
            #pragma unroll
            for (int i = 0; i < 2; ++i)
                #pragma unroll
                for (int j = 0; j < 4; ++j)
                    acc[i][j] = __builtin_amdgcn_mfma_f32_16x16x32_bf16(b[j], a[i], acc[i][j], 0, 0, 0);
        }
        asm volatile("s_waitcnt lgkmcnt(0)" ::: "memory");
        __builtin_amdgcn_s_barrier();
        cur ^= 1;
    }

    // epilogue: lane holds 4 consecutive H-cols of one token -> float4 stores
    int w4 = x16 * 4;
    #pragma unroll
    for (int i = 0; i < 2; ++i) {
        int rl = mb + i * 16 + lr;
        int p = m0 + rl;
        if (p < segEnd) {
            int tok = stokL[rl];
            float g = gsL[rl];
            #pragma unroll
            for (int j = 0; j < 4; ++j) {
                int gc = n0 + nb + j * 16 + w4;
                float4 bias = *(const float4*)(b2 + e * H + gc);
                float4 res;
                res.x = g * (acc[i][j][0] + bias.x);
                res.y = g * (acc[i][j][1] + bias.y);
                res.z = g * (acc[i][j][2] + bias.z);
                res.w = g * (acc[i][j][3] + bias.w);
                *(float4*)(out + (size_t)tok * H + gc) = res;
            }
        }
    }
}

extern "C" void kernel_launch(void* const* d_in, const int* in_sizes, int n_in,
                              void* d_out, int out_size, void* d_ws, size_t ws_size,
                              hipStream_t stream) {
    const float* x  = (const float*)d_in[0];
    const float* Wg = (const float*)d_in[1];
    const float* W1 = (const float*)d_in[2];
    const float* b1 = (const float*)d_in[3];
    const float* W2 = (const float*)d_in[4];
    const float* b2 = (const float*)d_in[5];
    float* out = (float*)d_out;

    char* ws = (char*)d_ws;
    unsigned short* xg  = (unsigned short*)(ws + 0);          //  8 MB
    unsigned short* w1t = (unsigned short*)(ws + 8388608);    // 16 MB
    unsigned short* w2t = (unsigned short*)(ws + 25165824);   // 16 MB
    unsigned short* hbf = (unsigned short*)(ws + 41943040);   // 32 MB
    float* gate = (float*)(ws + 75497472);                    // 32 KB
    float* gs   = (float*)(ws + 75530240);                    // 32 KB
    int* stok   = (int*)(ws + 75563008);                      // 32 KB
    int* list   = (int*)(ws + 75595776);                      // 128 KB
    int* cnt    = (int*)(ws + 75726848);                      // 64 B
    float* pprob= (float*)(ws + 75726976);                    // 8 KB

    float* outlb = out + (size_t)NTOK * H;
    hipMemsetAsync(cnt, 0, 8 * sizeof(int), stream);
    prep_kernel<<<4352, 256, 0, stream>>>(W1, w1t, W2, w2t, x, Wg, gate, list, cnt, pprob);
    gather_kernel<<<2048, 256, 0, stream>>>(x, gate, list, cnt, pprob, xg, gs, stok, outlb);
    gemm1_kernel<<<4096, 256, 0, stream>>>(xg, w1t, b1, cnt, hbf);
    gemm2_kernel<<<2048, 256, 0, stream>>>(hbf, w2t, b2, cnt, gs, stok, out);
}

// Round 11
// 111.118 us; speedup vs baseline: 1.4054x; 1.0153x over previous
//
#include <hip/hip_runtime.h>
#include <hip/hip_bf16.h>
#include <stdint.h>

#define H 512
#define F 2048
#define E 8
#define NTOK 8192
#define LSTRIDE 4096

typedef __bf16 bf16x8 __attribute__((ext_vector_type(8)));
typedef float f32x4 __attribute__((ext_vector_type(4)));

__device__ __forceinline__ unsigned short f2bf(float f) {
    unsigned u = __builtin_bit_cast(unsigned, f);
    u += 0x7FFFu + ((u >> 16) & 1u);
    return (unsigned short)(u >> 16);
}

__device__ __forceinline__ void gl_lds16(const unsigned short* g, unsigned short* l) {
    __builtin_amdgcn_global_load_lds(
        (const __attribute__((address_space(1))) unsigned int*)g,
        (__attribute__((address_space(3))) unsigned int*)l,
        16, 0, 0);
}

// 64x64 tile transpose via pair-packed LDS (tp = 64*33 u32 = 8448 B scratch)
// src [R][C] fp32 -> dst [C][R] bf16. All LDS ops b32; global stores full 128B lines.
__device__ __forceinline__ void transpose_tile(const float* __restrict__ src,
                                               unsigned short* __restrict__ dst,
                                               int R, int C, int r0, int c0,
                                               unsigned* tp, int tid) {
    int cg = tid & 15, r2b = tid >> 4;        // cg: 4-col group; r2b: row-pair 0..15
    #pragma unroll
    for (int p = 0; p < 2; ++p) {
        int r2 = p * 16 + r2b;                // row-pair 0..31
        const float* s0 = src + (size_t)(r0 + 2 * r2) * C + c0 + cg * 4;
        float4 v0 = *(const float4*)s0;
        float4 v1 = *(const float4*)(s0 + C);
        tp[(cg * 4 + 0) * 33 + r2] = (unsigned)f2bf(v0.x) | ((unsigned)f2bf(v1.x) << 16);
        tp[(cg * 4 + 1) * 33 + r2] = (unsigned)f2bf(v0.y) | ((unsigned)f2bf(v1.y) << 16);
        tp[(cg * 4 + 2) * 33 + r2] = (unsigned)f2bf(v0.z) | ((unsigned)f2bf(v1.z) << 16);
        tp[(cg * 4 + 3) * 33 + r2] = (unsigned)f2bf(v0.w) | ((unsigned)f2bf(v1.w) << 16);
    }
    __syncthreads();
    int och = tid & 7;
    #pragma unroll
    for (int q = 0; q < 2; ++q) {
        int oc = q * 32 + (tid >> 3);          // output row (= input col) 0..63
        unsigned m0 = tp[oc * 33 + och * 4 + 0];
        unsigned m1 = tp[oc * 33 + och * 4 + 1];
        unsigned m2 = tp[oc * 33 + och * 4 + 2];
        unsigned m3 = tp[oc * 33 + och * 4 + 3];
        uint4 uv; uv.x = m0; uv.y = m1; uv.z = m2; uv.w = m3;
        *(uint4*)(dst + (size_t)(c0 + oc) * R + r0 + och * 8) = uv;
    }
}

// ---------- prep: blocks [0,2048) W1 transpose, [2048,2304) router ----------
__global__ void prep_kernel(const float* __restrict__ W1, unsigned short* __restrict__ w1t,
                            const float* __restrict__ x, const float* __restrict__ Wg,
                            float* __restrict__ gate, int* __restrict__ list,
                            int* __restrict__ cnt, float* __restrict__ pprob) {
    __shared__ float wg[H * E];        // router weights; transpose path aliases as tp
    __shared__ float lg[32][8];
    __shared__ int am_l[32];
    __shared__ int rank_l[32];
    __shared__ int eb[8];
    int tid = threadIdx.x;

    if (blockIdx.x < 2048) {
        int id = blockIdx.x;
        int z = id >> 8;                       // expert
        int r0 = ((id >> 5) & 7) * 64, c0 = (id & 31) * 64;   // R=512, C=2048
        transpose_tile(W1 + (size_t)z * 512 * 2048, w1t + (size_t)z * 512 * 2048,
                       512, 2048, r0, c0, (unsigned*)wg, tid);
        return;
    }

    // ---- router ----
    int rbid = blockIdx.x - 2048;
    #pragma unroll
    for (int p = 0; p < 16; ++p) wg[p * 256 + tid] = Wg[p * 256 + tid];
    __syncthreads();

    int tl = tid >> 3, e = tid & 7;
    int token = rbid * 32 + tl;
    const float4* x4 = (const float4*)(x + (size_t)token * H);
    float acc = 0.f;
    for (int kq = 0; kq < 128; ++kq) {
        float4 v = x4[kq];
        acc += v.x * wg[(kq * 4 + 0) * 8 + e];
        acc += v.y * wg[(kq * 4 + 1) * 8 + e];
        acc += v.z * wg[(kq * 4 + 2) * 8 + e];
        acc += v.w * wg[(kq * 4 + 3) * 8 + e];
    }
    lg[tl][e] = acc;
    __syncthreads();

    if (tid < 32) {
        float l[8];
        #pragma unroll
        for (int q = 0; q < 8; ++q) l[q] = lg[tid][q];
        float mx = l[0];
        #pragma unroll
        for (int q = 1; q < 8; ++q) mx = fmaxf(mx, l[q]);
        float p[8]; float s = 0.f;
        #pragma unroll
        for (int q = 0; q < 8; ++q) { p[q] = expf(l[q] - mx); s += p[q]; }
        int am = 0; float best = l[0];
        #pragma unroll
        for (int q = 1; q < 8; ++q) if (l[q] > best) { best = l[q]; am = q; }
        float inv = 1.f / s;
        #pragma unroll
        for (int q = 0; q < 8; ++q) lg[tid][q] = p[q] * inv;
        float sp = p[am] * inv;
        gate[rbid * 32 + tid] = sp / (sp + 1e-8f);
        am_l[tid] = am;
    }
    __syncthreads();

    if (tid < 8) {
        float s = 0.f;
        for (int i = 0; i < 32; ++i) s += lg[i][tid];
        pprob[rbid * 8 + tid] = s;
        int c = 0;
        for (int i = 0; i < 32; ++i) if (am_l[i] == tid) rank_l[i] = c++;
        eb[tid] = atomicAdd(&cnt[tid], c);
    }
    __syncthreads();

    if (tid < 32) {
        int e2 = am_l[tid];
        int pos = eb[e2] + rank_l[tid];
        if (pos < LSTRIDE) list[e2 * LSTRIDE + pos] = rbid * 32 + tid;
    }
}

__device__ __forceinline__ void load_ebase(const int* __restrict__ cnt, int* eb) {
    int b = 0;
    #pragma unroll
    for (int q = 0; q < 8; ++q) { eb[q] = b; b += cnt[q]; }
}

// ---------- gather: x -> xg (bf16, expert-sorted) + gs/stok; block 0 computes lb ----------
__global__ void gather_kernel(const float* __restrict__ x, const float* __restrict__ gate,
                              const int* __restrict__ list, const int* __restrict__ cnt,
                              const float* __restrict__ pprob,
                              unsigned short* __restrict__ xg, float* __restrict__ gs,
                              int* __restrict__ stok, float* __restrict__ outlb) {
    __shared__ float lbp[8];
    int eb[8];
    load_ebase(cnt, eb);
    if (blockIdx.x == 0) {
        if (threadIdx.x < 8) {
            int t = threadIdx.x;
            float acc = 0.f;
            for (int i = 0; i < 256; ++i) acc += pprob[i * 8 + t];
            lbp[t] = acc * (float)cnt[t];
        }
        __syncthreads();
        if (threadIdx.x == 0) {
            float tot = 0.f;
            #pragma unroll
            for (int q = 0; q < 8; ++q) tot += lbp[q];
            outlb[0] = tot * (8.0f / ((float)NTOK * (float)NTOK));
        }
    }
    int p = blockIdx.x * 4 + (threadIdx.x >> 6);
    int lane = threadIdx.x & 63;
    int e = 0;
    #pragma unroll
    for (int q = 1; q < 8; ++q) if (p >= eb[q]) e = q;
    int token = list[e * LSTRIDE + (p - eb[e])];
    const float4* src = (const float4*)(x + (size_t)token * H) + lane * 2;
    float4 a = src[0], b = src[1];
    uint4 u;
    u.x = (unsigned)f2bf(a.x) | ((unsigned)f2bf(a.y) << 16);
    u.y = (unsigned)f2bf(a.z) | ((unsigned)f2bf(a.w) << 16);
    u.z = (unsigned)f2bf(b.x) | ((unsigned)f2bf(b.y) << 16);
    u.w = (unsigned)f2bf(b.z) | ((unsigned)f2bf(b.w) << 16);
    *(uint4*)(xg + (size_t)p * H + lane * 8) = u;
    if (lane == 0) { stok[p] = token; gs[p] = gate[token]; }
}

// ---------- GEMM1 (+ overlapped W2 transpose): blocks [0,4096) gemm, [4096,6144) transpose ----------
__global__ __launch_bounds__(256, 2) void gemm1_kernel(
    const unsigned short* __restrict__ xg,    // [NTOK][H] sorted
    const unsigned short* __restrict__ w1t,   // [E][F][H]
    const float* __restrict__ b1,
    const int* __restrict__ cnt,
    const float* __restrict__ W2, unsigned short* __restrict__ w2t,
    unsigned short* __restrict__ hbf)         // [NTOK][F] sorted
{
    __shared__ unsigned short Al[2][128 * 64];   // 2 x 16 KB
    __shared__ unsigned short Bl[2][128 * 64];   // 2 x 16 KB
    int tid = threadIdx.x;

    if (blockIdx.x >= 4096) {
        // ---- W2 transpose: [8][2048][512] -> w2t [8][512][2048] ----
        int id = blockIdx.x - 4096;
        int z = id >> 8;
        int r0 = (id & 31) * 64, c0 = ((id >> 5) & 7) * 64;   // R=2048, C=512
        transpose_tile(W2 + (size_t)z * 2048 * 512, w2t + (size_t)z * 2048 * 512,
                       2048, 512, r0, c0, (unsigned*)&Al[0][0], tid);
        return;
    }

    int bid = blockIdx.x;
    int e = bid & 7;                 // expert -> XCD
    int idx = bid >> 3;              // 0..511
    int mblk = idx >> 4;             // 0..31, m-major
    int c = cnt[e];
    if (mblk * 128 >= c) return;
    int n0 = (idx & 15) * 128;       // n fastest -> same-XCD A-tile reuse
    int eb[8]; load_ebase(cnt, eb);
    int m0 = eb[e] + mblk * 128;
    int segEnd = eb[e] + c;

    int lane = tid & 63, w = tid >> 6;
    int lr8 = lane >> 3, lch = lane & 7;
    int swc = lch ^ lr8;                       // source-side chunk swizzle

    const unsigned short* asrc[4];
    const unsigned short* bsrc[4];
    #pragma unroll
    for (int i = 0; i < 4; ++i) {
        int seg = w * 4 + i;
        int row = seg * 8 + lr8;
        int ar = m0 + row; if (ar > NTOK - 1) ar = NTOK - 1;
        asrc[i] = xg + (size_t)ar * H + swc * 8;
        bsrc[i] = w1t + ((size_t)e * F + n0 + row) * H + swc * 8;
    }

    f32x4 acc[4][4] = {};
    int mb = (w >> 1) * 64, nb = (w & 1) * 64;
    int lr = lane & 15, x16 = lane >> 4;
    int sw = (lr & 7) << 4;                    // read-side byte XOR

    // prologue: stage tile 0 into buf 0 (8 loads/thread in flight)
    #pragma unroll
    for (int i = 0; i < 4; ++i) {
        gl_lds16(asrc[i], &Al[0][(w * 4 + i) * 512]);
        gl_lds16(bsrc[i], &Bl[0][(w * 4 + i) * 512]);
    }

    int cur = 0;
    #pragma unroll
    for (int t = 0; t < 8; ++t) {
        if (t < 7) {
            int k0 = (t + 1) * 64;
            #pragma unroll
            for (int i = 0; i < 4; ++i) {
                gl_lds16(asrc[i] + k0, &Al[cur ^ 1][(w * 4 + i) * 512]);
                gl_lds16(bsrc[i] + k0, &Bl[cur ^ 1][(w * 4 + i) * 512]);
            }
            asm volatile("s_waitcnt vmcnt(8)" ::: "memory");  // tile t landed; t+1 in flight
        } else {
            asm volatile("s_waitcnt vmcnt(0)" ::: "memory");
        }
        __builtin_amdgcn_s_barrier();          // all waves' tile-t loads visible
        #pragma unroll
        for (int kk = 0; kk < 2; ++kk) {
            int co = (kk * 64 + x16 * 16) ^ sw;
            bf16x8 a[4], b[4];
            #pragma unroll
            for (int i = 0; i < 4; ++i)
                a[i] = *(const bf16x8*)((const char*)Al[cur] + (mb + i * 16 + lr) * 128 + co);
            #pragma unroll
            for (int j = 0; j < 4; ++j)
                b[j] = *(const bf16x8*)((const char*)Bl[cur] + (nb + j * 16 + lr) * 128 + co);
            #pragma unroll
            for (int i = 0; i < 4; ++i)
                #pragma unroll
                for (int j = 0; j < 4; ++j)
                    acc[i][j] = __builtin_amdgcn_mfma_f32_16x16x32_bf16(b[j], a[i], acc[i][j], 0, 0, 0);
        }
        asm volatile("s_waitcnt lgkmcnt(0)" ::: "memory");    // done reading buf[cur]
        __builtin_amdgcn_s_barrier();          // before next iter overwrites it
        cur ^= 1;
    }

    // epilogue: lane holds 4 consecutive F-cols of one token -> 8B packed stores
    int w4 = x16 * 4;
    #pragma unroll
    for (int j = 0; j < 4; ++j) {
        int gc = n0 + nb + j * 16 + w4;
        float4 bias = *(const float4*)(b1 + e * F + gc);
        #pragma unroll
        for (int i = 0; i < 4; ++i) {
            int p = m0 + mb + i * 16 + lr;
            if (p < segEnd) {
                float v0 = acc[i][j][0] + bias.x; v0 = v0 > 0.f ? v0 : 0.f;
                float v1 = acc[i][j][1] + bias.y; v1 = v1 > 0.f ? v1 : 0.f;
                float v2 = acc[i][j][2] + bias.z; v2 = v2 > 0.f ? v2 : 0.f;
                float v3 = acc[i][j][3] + bias.w; v3 = v3 > 0.f ? v3 : 0.f;
                uint2 pk;
                pk.x = (unsigned)f2bf(v0) | ((unsigned)f2bf(v1) << 16);
                pk.y = (unsigned)f2bf(v2) | ((unsigned)f2bf(v3) << 16);
                *(uint2*)(hbf + (size_t)p * F + gc) = pk;
            }
        }
    }
}

// ---------- GEMM2: out = gate*(h @ W2t^T + b2) scattered, 64x128xBK64, counted-vmcnt(6), 3/CU ----------
__global__ __launch_bounds__(256, 3) void gemm2_kernel(
    const unsigned short* __restrict__ hbf,   // [NTOK][F] sorted
    const unsigned short* __restrict__ w2t,   // [E][H][F]
    const float* __restrict__ b2,
    const int* __restrict__ cnt,
    const float* __restrict__ gs, const int* __restrict__ stok,
    float* __restrict__ out)                  // [NTOK][H] token order
{
    int bid = blockIdx.x;
    int e = bid & 7;
    int idx = bid >> 3;              // 0..255
    int mblk = idx >> 2;             // 0..63
    int c = cnt[e];
    if (mblk * 64 >= c) return;
    int n0 = (idx & 3) * 128;
    int eb[8]; load_ebase(cnt, eb);
    int m0 = eb[e] + mblk * 64;
    int segEnd = eb[e] + c;

    __shared__ unsigned short Al[2][64 * 64];    // 2 x 8 KB
    __shared__ unsigned short Bl[2][128 * 64];   // 2 x 16 KB
    __shared__ int stokL[64];
    __shared__ float gsL[64];

    int tid = threadIdx.x, lane = tid & 63, w = tid >> 6;
    if (tid < 64) {
        int p = m0 + tid;
        int pc = p > NTOK - 1 ? NTOK - 1 : p;
        stokL[tid] = stok[pc];
        gsL[tid] = gs[pc];
    }
    int lr8 = lane >> 3, lch = lane & 7;
    int swc = lch ^ lr8;

    const unsigned short* asrc[2];
    const unsigned short* bsrc[4];
    #pragma unroll
    for (int i = 0; i < 2; ++i) {
        int row = (w * 2 + i) * 8 + lr8;
        int ar = m0 + row; if (ar > NTOK - 1) ar = NTOK - 1;
        asrc[i] = hbf + (size_t)ar * F + swc * 8;
    }
    #pragma unroll
    for (int i = 0; i < 4; ++i) {
        int row = (w * 4 + i) * 8 + lr8;
        bsrc[i] = w2t + ((size_t)e * H + n0 + row) * F + swc * 8;
    }

    f32x4 acc[2][4] = {};
    int mb = (w >> 1) * 32, nb = (w & 1) * 64;
    int lr = lane & 15, x16 = lane >> 4;
    int sw = (lr & 7) << 4;

    // prologue: 6 loads/thread
    #pragma unroll
    for (int i = 0; i < 2; ++i) gl_lds16(asrc[i], &Al[0][(w * 2 + i) * 512]);
    #pragma unroll
    for (int i = 0; i < 4; ++i) gl_lds16(bsrc[i], &Bl[0][(w * 4 + i) * 512]);
    __builtin_amdgcn_s_barrier();   // stokL/gsL visibility

    int cur = 0;
    #pragma unroll
    for (int t = 0; t < 32; ++t) {
        if (t < 31) {
            int k0 = (t + 1) * 64;
            #pragma unroll
            for (int i = 0; i < 2; ++i) gl_lds16(asrc[i] + k0, &Al[cur ^ 1][(w * 2 + i) * 512]);
            #pragma unroll
            for (int i = 0; i < 4; ++i) gl_lds16(bsrc[i] + k0, &Bl[cur ^ 1][(w * 4 + i) * 512]);
            asm volatile("s_waitcnt vmcnt(6)" ::: "memory");   // tile t landed; t+1 in flight
        } else {
            asm volatile("s_waitcnt vmcnt(0)" ::: "memory");
        }
        __builtin_amdgcn_s_barrier();
        #pragma unroll
        for (int kk = 0; kk < 2; ++kk) {
            int co = (kk * 64 + x16 * 16) ^ sw;
            bf16x8 a[2], b[4];
            #pragma unroll
            for (int i = 0; i < 2; ++i)
                a[i] = *(const bf16x8*)((const char*)Al[cur] + (mb + i * 16 + lr) * 128 + co);
            #pragma unroll
            for (int j = 0; j < 4; ++j)
                b[j] = *(const bf16x8*)((const char*)Bl[cur] + (nb + j * 16 + lr) * 128 + co);
            #pragma unroll
            for (int i = 0; i < 2; ++i)
                #pragma unroll
                for (int j = 0; j < 4; ++j)
                    acc[i][j] = __builtin_amdgcn_mfma_f32_16x16x32_bf16(b[j], a[i], acc[i][j], 0, 0, 0);
        }
        asm volatile("s_waitcnt lgkmcnt(0)" ::: "memory");
        __builtin_amdgcn_s_barrier();
        cur ^= 1;
    }

    // epilogue: lane holds 4 consecutive H-cols of one token -> float4 stores
    int w4 = x16 * 4;
    #pragma unroll
    for (int i = 0; i < 2; ++i) {
        int rl = mb + i * 16 + lr;
        int p = m0 + rl;
        if (p < segEnd) {
            int tok = stokL[rl];
            float g = gsL[rl];
            #pragma unroll
            for (int j = 0; j < 4; ++j) {
                int gc = n0 + nb + j * 16 + w4;
                float4 bias = *(const float4*)(b2 + e * H + gc);
                float4 res;
                res.x = g * (acc[i][j][0] + bias.x);
                res.y = g * (acc[i][j][1] + bias.y);
                res.z = g * (acc[i][j][2] + bias.z);
                res.w = g * (acc[i][j][3] + bias.w);
                *(float4*)(out + (size_t)tok * H + gc) = res;
            }
        }
    }
}

extern "C" void kernel_launch(void* const* d_in, const int* in_sizes, int n_in,
                              void* d_out, int out_size, void* d_ws, size_t ws_size,
                              hipStream_t stream) {
    const float* x  = (const float*)d_in[0];
    const float* Wg = (const float*)d_in[1];
    const float* W1 = (const float*)d_in[2];
    const float* b1 = (const float*)d_in[3];
    const float* W2 = (const float*)d_in[4];
    const float* b2 = (const float*)d_in[5];
    float* out = (float*)d_out;

    char* ws = (char*)d_ws;
    unsigned short* xg  = (unsigned short*)(ws + 0);          //  8 MB
    unsigned short* w1t = (unsigned short*)(ws + 8388608);    // 16 MB
    unsigned short* w2t = (unsigned short*)(ws + 25165824);   // 16 MB
    unsigned short* hbf = (unsigned short*)(ws + 41943040);   // 32 MB
    float* gate = (float*)(ws + 75497472);                    // 32 KB
    float* gs   = (float*)(ws + 75530240);                    // 32 KB
    int* stok   = (int*)(ws + 75563008);                      // 32 KB
    int* list   = (int*)(ws + 75595776);                      // 128 KB
    int* cnt    = (int*)(ws + 75726848);                      // 64 B
    float* pprob= (float*)(ws + 75726976);                    // 8 KB

    float* outlb = out + (size_t)NTOK * H;
    hipMemsetAsync(cnt, 0, 8 * sizeof(int), stream);
    prep_kernel<<<2304, 256, 0, stream>>>(W1, w1t, x, Wg, gate, list, cnt, pprob);
    gather_kernel<<<2048, 256, 0, stream>>>(x, gate, list, cnt, pprob, xg, gs, stok, outlb);
    gemm1_kernel<<<6144, 256, 0, stream>>>(xg, w1t, b1, cnt, W2, w2t, hbf);
    gemm2_kernel<<<2048, 256, 0, stream>>>(hbf, w2t, b2, cnt, gs, stok, out);
}

// Round 12
// 105.923 us; speedup vs baseline: 1.4743x; 1.0490x over previous
//
#include <hip/hip_runtime.h>
#include <hip/hip_bf16.h>
#include <stdint.h>

#define H 512
#define F 2048
#define E 8
#define NTOK 8192
#define LSTRIDE 4096

typedef __bf16 bf16x8 __attribute__((ext_vector_type(8)));
typedef float f32x4 __attribute__((ext_vector_type(4)));

__device__ __forceinline__ unsigned short f2bf(float f) {
    unsigned u = __builtin_bit_cast(unsigned, f);
    u += 0x7FFFu + ((u >> 16) & 1u);
    return (unsigned short)(u >> 16);
}

__device__ __forceinline__ void gl_lds16(const unsigned short* g, unsigned short* l) {
    __builtin_amdgcn_global_load_lds(
        (const __attribute__((address_space(1))) unsigned int*)g,
        (__attribute__((address_space(3))) unsigned int*)l,
        16, 0, 0);
}

// 64x64 tile transpose via pair-packed LDS (tp = 64*33 u32 = 8448 B scratch)
__device__ __forceinline__ void transpose_tile(const float* __restrict__ src,
                                               unsigned short* __restrict__ dst,
                                               int R, int C, int r0, int c0,
                                               unsigned* tp, int tid) {
    int cg = tid & 15, r2b = tid >> 4;
    #pragma unroll
    for (int p = 0; p < 2; ++p) {
        int r2 = p * 16 + r2b;
        const float* s0 = src + (size_t)(r0 + 2 * r2) * C + c0 + cg * 4;
        float4 v0 = *(const float4*)s0;
        float4 v1 = *(const float4*)(s0 + C);
        tp[(cg * 4 + 0) * 33 + r2] = (unsigned)f2bf(v0.x) | ((unsigned)f2bf(v1.x) << 16);
        tp[(cg * 4 + 1) * 33 + r2] = (unsigned)f2bf(v0.y) | ((unsigned)f2bf(v1.y) << 16);
        tp[(cg * 4 + 2) * 33 + r2] = (unsigned)f2bf(v0.z) | ((unsigned)f2bf(v1.z) << 16);
        tp[(cg * 4 + 3) * 33 + r2] = (unsigned)f2bf(v0.w) | ((unsigned)f2bf(v1.w) << 16);
    }
    __syncthreads();
    int och = tid & 7;
    #pragma unroll
    for (int q = 0; q < 2; ++q) {
        int oc = q * 32 + (tid >> 3);
        uint4 uv;
        uv.x = tp[oc * 33 + och * 4 + 0];
        uv.y = tp[oc * 33 + och * 4 + 1];
        uv.z = tp[oc * 33 + och * 4 + 2];
        uv.w = tp[oc * 33 + och * 4 + 3];
        *(uint4*)(dst + (size_t)(c0 + oc) * R + r0 + och * 8) = uv;
    }
}

// ---------- router ----------
__global__ void router_kernel(const float* __restrict__ x, const float* __restrict__ Wg,
                              float* __restrict__ gate, int* __restrict__ list,
                              int* __restrict__ cnt, float* __restrict__ pprob) {
    __shared__ float wg[H * E];
    __shared__ float lg[32][8];
    __shared__ int am_l[32];
    __shared__ int rank_l[32];
    __shared__ int eb[8];
    int tid = threadIdx.x;

    #pragma unroll
    for (int p = 0; p < 16; ++p) wg[p * 256 + tid] = Wg[p * 256 + tid];
    __syncthreads();

    int tl = tid >> 3, e = tid & 7;
    int token = blockIdx.x * 32 + tl;
    const float4* x4 = (const float4*)(x + (size_t)token * H);
    float acc = 0.f;
    for (int kq = 0; kq < 128; ++kq) {
        float4 v = x4[kq];
        acc += v.x * wg[(kq * 4 + 0) * 8 + e];
        acc += v.y * wg[(kq * 4 + 1) * 8 + e];
        acc += v.z * wg[(kq * 4 + 2) * 8 + e];
        acc += v.w * wg[(kq * 4 + 3) * 8 + e];
    }
    lg[tl][e] = acc;
    __syncthreads();

    if (tid < 32) {
        float l[8];
        #pragma unroll
        for (int q = 0; q < 8; ++q) l[q] = lg[tid][q];
        float mx = l[0];
        #pragma unroll
        for (int q = 1; q < 8; ++q) mx = fmaxf(mx, l[q]);
        float p[8]; float s = 0.f;
        #pragma unroll
        for (int q = 0; q < 8; ++q) { p[q] = expf(l[q] - mx); s += p[q]; }
        int am = 0; float best = l[0];
        #pragma unroll
        for (int q = 1; q < 8; ++q) if (l[q] > best) { best = l[q]; am = q; }
        float inv = 1.f / s;
        #pragma unroll
        for (int q = 0; q < 8; ++q) lg[tid][q] = p[q] * inv;
        float sp = p[am] * inv;
        gate[blockIdx.x * 32 + tid] = sp / (sp + 1e-8f);
        am_l[tid] = am;
    }
    __syncthreads();

    if (tid < 8) {
        float s = 0.f;
        for (int i = 0; i < 32; ++i) s += lg[i][tid];
        pprob[blockIdx.x * 8 + tid] = s;
        int c = 0;
        for (int i = 0; i < 32; ++i) if (am_l[i] == tid) rank_l[i] = c++;
        eb[tid] = atomicAdd(&cnt[tid], c);
    }
    __syncthreads();

    if (tid < 32) {
        int e2 = am_l[tid];
        int pos = eb[e2] + rank_l[tid];
        if (pos < LSTRIDE) list[e2 * LSTRIDE + pos] = blockIdx.x * 32 + tid;
    }
}

__device__ __forceinline__ void load_ebase(const int* __restrict__ cnt, int* eb) {
    int b = 0;
    #pragma unroll
    for (int q = 0; q < 8; ++q) { eb[q] = b; b += cnt[q]; }
}

// ---------- gather + W1 transpose: blocks [0,2048) gather, [2048,4096) W1T ----------
__global__ void gather_kernel(const float* __restrict__ x, const float* __restrict__ gate,
                              const int* __restrict__ list, const int* __restrict__ cnt,
                              const float* __restrict__ pprob,
                              const float* __restrict__ W1, unsigned short* __restrict__ w1t,
                              unsigned short* __restrict__ xg, float* __restrict__ gs,
                              int* __restrict__ stok, float* __restrict__ outlb) {
    __shared__ unsigned tp[64 * 33];   // transpose scratch (8448 B)
    __shared__ float lbp[8];
    int tid = threadIdx.x;

    if (blockIdx.x >= 2048) {
        int id = blockIdx.x - 2048;
        int z = id >> 8;
        int r0 = ((id >> 5) & 7) * 64, c0 = (id & 31) * 64;   // R=512, C=2048
        transpose_tile(W1 + (size_t)z * 512 * 2048, w1t + (size_t)z * 512 * 2048,
                       512, 2048, r0, c0, tp, tid);
        return;
    }

    int eb[8];
    load_ebase(cnt, eb);
    if (blockIdx.x == 0) {
        if (tid < 8) {
            float acc = 0.f;
            for (int i = 0; i < 256; ++i) acc += pprob[i * 8 + tid];
            lbp[tid] = acc * (float)cnt[tid];
        }
        __syncthreads();
        if (tid == 0) {
            float tot = 0.f;
            #pragma unroll
            for (int q = 0; q < 8; ++q) tot += lbp[q];
            outlb[0] = tot * (8.0f / ((float)NTOK * (float)NTOK));
        }
    }
    int p = blockIdx.x * 4 + (tid >> 6);
    int lane = tid & 63;
    int e = 0;
    #pragma unroll
    for (int q = 1; q < 8; ++q) if (p >= eb[q]) e = q;
    int token = list[e * LSTRIDE + (p - eb[e])];
    const float4* src = (const float4*)(x + (size_t)token * H) + lane * 2;
    float4 a = src[0], b = src[1];
    uint4 u;
    u.x = (unsigned)f2bf(a.x) | ((unsigned)f2bf(a.y) << 16);
    u.y = (unsigned)f2bf(a.z) | ((unsigned)f2bf(a.w) << 16);
    u.z = (unsigned)f2bf(b.x) | ((unsigned)f2bf(b.y) << 16);
    u.w = (unsigned)f2bf(b.z) | ((unsigned)f2bf(b.w) << 16);
    *(uint4*)(xg + (size_t)p * H + lane * 8) = u;
    if (lane == 0) { stok[p] = token; gs[p] = gate[token]; }
}

// ---------- GEMM1 (+W2T tail): h = relu(xg @ W1t^T + b1), 64x128xBK64, 3/CU, vmcnt(6) ----------
__global__ __launch_bounds__(256, 3) void gemm1_kernel(
    const unsigned short* __restrict__ xg,    // [NTOK][H] sorted
    const unsigned short* __restrict__ w1t,   // [E][F][H]
    const float* __restrict__ b1,
    const int* __restrict__ cnt,
    const float* __restrict__ W2, unsigned short* __restrict__ w2t,
    unsigned short* __restrict__ hbf)         // [NTOK][F] sorted
{
    __shared__ unsigned short Al[2][64 * 64];    // 2 x 8 KB
    __shared__ unsigned short Bl[2][128 * 64];   // 2 x 16 KB
    int tid = threadIdx.x;

    if (blockIdx.x >= 8192) {
        // ---- W2 transpose: [8][2048][512] -> w2t [8][512][2048] ----
        int id = blockIdx.x - 8192;
        int z = id >> 8;
        int r0 = (id & 31) * 64, c0 = ((id >> 5) & 7) * 64;   // R=2048, C=512
        transpose_tile(W2 + (size_t)z * 2048 * 512, w2t + (size_t)z * 2048 * 512,
                       2048, 512, r0, c0, (unsigned*)&Al[0][0], tid);
        return;
    }

    int bid = blockIdx.x;
    int e = bid & 7;                 // expert -> XCD
    int idx = bid >> 3;              // 0..1023
    int mblk = idx >> 4;             // 0..63, m-major
    int c = cnt[e];
    if (mblk * 64 >= c) return;
    int n0 = (idx & 15) * 128;       // n fastest -> same-XCD A-tile reuse
    int eb[8]; load_ebase(cnt, eb);
    int m0 = eb[e] + mblk * 64;
    int segEnd = eb[e] + c;

    int lane = tid & 63, w = tid >> 6;
    int lr8 = lane >> 3, lch = lane & 7;
    int swc = lch ^ lr8;                       // source-side chunk swizzle

    const unsigned short* asrc[2];
    const unsigned short* bsrc[4];
    #pragma unroll
    for (int i = 0; i < 2; ++i) {
        int row = (w * 2 + i) * 8 + lr8;
        int ar = m0 + row; if (ar > NTOK - 1) ar = NTOK - 1;
        asrc[i] = xg + (size_t)ar * H + swc * 8;
    }
    #pragma unroll
    for (int i = 0; i < 4; ++i) {
        int row = (w * 4 + i) * 8 + lr8;
        bsrc[i] = w1t + ((size_t)e * F + n0 + row) * H + swc * 8;
    }

    f32x4 acc[2][4] = {};
    int mb = (w >> 1) * 32, nb = (w & 1) * 64;
    int lr = lane & 15, x16 = lane >> 4;
    int sw = (lr & 7) << 4;                    // read-side byte XOR

    // prologue: 6 loads/thread
    #pragma unroll
    for (int i = 0; i < 2; ++i) gl_lds16(asrc[i], &Al[0][(w * 2 + i) * 512]);
    #pragma unroll
    for (int i = 0; i < 4; ++i) gl_lds16(bsrc[i], &Bl[0][(w * 4 + i) * 512]);

    int cur = 0;
    #pragma unroll
    for (int t = 0; t < 8; ++t) {
        if (t < 7) {
            int k0 = (t + 1) * 64;
            #pragma unroll
            for (int i = 0; i < 2; ++i) gl_lds16(asrc[i] + k0, &Al[cur ^ 1][(w * 2 + i) * 512]);
            #pragma unroll
            for (int i = 0; i < 4; ++i) gl_lds16(bsrc[i] + k0, &Bl[cur ^ 1][(w * 4 + i) * 512]);
            asm volatile("s_waitcnt vmcnt(6)" ::: "memory");   // tile t landed; t+1 in flight
        } else {
            asm volatile("s_waitcnt vmcnt(0)" ::: "memory");
        }
        __builtin_amdgcn_s_barrier();
        #pragma unroll
        for (int kk = 0; kk < 2; ++kk) {
            int co = (kk * 64 + x16 * 16) ^ sw;
            bf16x8 a[2], b[4];
            #pragma unroll
            for (int i = 0; i < 2; ++i)
                a[i] = *(const bf16x8*)((const char*)Al[cur] + (mb + i * 16 + lr) * 128 + co);
            #pragma unroll
            for (int j = 0; j < 4; ++j)
                b[j] = *(const bf16x8*)((const char*)Bl[cur] + (nb + j * 16 + lr) * 128 + co);
            #pragma unroll
            for (int i = 0; i < 2; ++i)
                #pragma unroll
                for (int j = 0; j < 4; ++j)
                    acc[i][j] = __builtin_amdgcn_mfma_f32_16x16x32_bf16(b[j], a[i], acc[i][j], 0, 0, 0);
        }
        asm volatile("s_waitcnt lgkmcnt(0)" ::: "memory");
        __builtin_amdgcn_s_barrier();
        cur ^= 1;
    }

    // epilogue: lane holds 4 consecutive F-cols of one token -> 8B packed stores
    int w4 = x16 * 4;
    #pragma unroll
    for (int j = 0; j < 4; ++j) {
        int gc = n0 + nb + j * 16 + w4;
        float4 bias = *(const float4*)(b1 + e * F + gc);
        #pragma unroll
        for (int i = 0; i < 2; ++i) {
            int p = m0 + mb + i * 16 + lr;
            if (p < segEnd) {
                float v0 = acc[i][j][0] + bias.x; v0 = v0 > 0.f ? v0 : 0.f;
                float v1 = acc[i][j][1] + bias.y; v1 = v1 > 0.f ? v1 : 0.f;
                float v2 = acc[i][j][2] + bias.z; v2 = v2 > 0.f ? v2 : 0.f;
                float v3 = acc[i][j][3] + bias.w; v3 = v3 > 0.f ? v3 : 0.f;
                uint2 pk;
                pk.x = (unsigned)f2bf(v0) | ((unsigned)f2bf(v1) << 16);
                pk.y = (unsigned)f2bf(v2) | ((unsigned)f2bf(v3) << 16);
                *(uint2*)(hbf + (size_t)p * F + gc) = pk;
            }
        }
    }
}

// ---------- GEMM2: out = gate*(h @ W2t^T + b2) scattered, 64x128xBK64, 3/CU, vmcnt(6) ----------
__global__ __launch_bounds__(256, 3) void gemm2_kernel(
    const unsigned short* __restrict__ hbf,   // [NTOK][F] sorted
    const unsigned short* __restrict__ w2t,   // [E][H][F]
    const float* __restrict__ b2,
    const int* __restrict__ cnt,
    const float* __restrict__ gs, const int* __restrict__ stok,
    float* __restrict__ out)                  // [NTOK][H] token order
{
    int bid = blockIdx.x;
    int e = bid & 7;
    int idx = bid >> 3;              // 0..255
    int mblk = idx >> 2;             // 0..63
    int c = cnt[e];
    if (mblk * 64 >= c) return;
    int n0 = (idx & 3) * 128;
    int eb[8]; load_ebase(cnt, eb);
    int m0 = eb[e] + mblk * 64;
    int segEnd = eb[e] + c;

    __shared__ unsigned short Al[2][64 * 64];    // 2 x 8 KB
    __shared__ unsigned short Bl[2][128 * 64];   // 2 x 16 KB
    __shared__ int stokL[64];
    __shared__ float gsL[64];

    int tid = threadIdx.x, lane = tid & 63, w = tid >> 6;
    if (tid < 64) {
        int p = m0 + tid;
        int pc = p > NTOK - 1 ? NTOK - 1 : p;
        stokL[tid] = stok[pc];
        gsL[tid] = gs[pc];
    }
    int lr8 = lane >> 3, lch = lane & 7;
    int swc = lch ^ lr8;

    const unsigned short* asrc[2];
    const unsigned short* bsrc[4];
    #pragma unroll
    for (int i = 0; i < 2; ++i) {
        int row = (w * 2 + i) * 8 + lr8;
        int ar = m0 + row; if (ar > NTOK - 1) ar = NTOK - 1;
        asrc[i] = hbf + (size_t)ar * F + swc * 8;
    }
    #pragma unroll
    for (int i = 0; i < 4; ++i) {
        int row = (w * 4 + i) * 8 + lr8;
        bsrc[i] = w2t + ((size_t)e * H + n0 + row) * F + swc * 8;
    }

    f32x4 acc[2][4] = {};
    int mb = (w >> 1) * 32, nb = (w & 1) * 64;
    int lr = lane & 15, x16 = lane >> 4;
    int sw = (lr & 7) << 4;

    // prologue: 6 loads/thread
    #pragma unroll
    for (int i = 0; i < 2; ++i) gl_lds16(asrc[i], &Al[0][(w * 2 + i) * 512]);
    #pragma unroll
    for (int i = 0; i < 4; ++i) gl_lds16(bsrc[i], &Bl[0][(w * 4 + i) * 512]);
    __builtin_amdgcn_s_barrier();   // stokL/gsL visibility

    int cur = 0;
    #pragma unroll
    for (int t = 0; t < 32; ++t) {
        if (t < 31) {
            int k0 = (t + 1) * 64;
            #pragma unroll
            for (int i = 0; i < 2; ++i) gl_lds16(asrc[i] + k0, &Al[cur ^ 1][(w * 2 + i) * 512]);
            #pragma unroll
            for (int i = 0; i < 4; ++i) gl_lds16(bsrc[i] + k0, &Bl[cur ^ 1][(w * 4 + i) * 512]);
            asm volatile("s_waitcnt vmcnt(6)" ::: "memory");   // tile t landed; t+1 in flight
        } else {
            asm volatile("s_waitcnt vmcnt(0)" ::: "memory");
        }
        __builtin_amdgcn_s_barrier();
        #pragma unroll
        for (int kk = 0; kk < 2; ++kk) {
            int co = (kk * 64 + x16 * 16) ^ sw;
            bf16x8 a[2], b[4];
            #pragma unroll
            for (int i = 0; i < 2; ++i)
                a[i] = *(const bf16x8*)((const char*)Al[cur] + (mb + i * 16 + lr) * 128 + co);
            #pragma unroll
            for (int j = 0; j < 4; ++j)
                b[j] = *(const bf16x8*)((const char*)Bl[cur] + (nb + j * 16 + lr) * 128 + co);
            #pragma unroll
            for (int i = 0; i < 2; ++i)
                #pragma unroll
                for (int j = 0; j < 4; ++j)
                    acc[i][j] = __builtin_amdgcn_mfma_f32_16x16x32_bf16(b[j], a[i], acc[i][j], 0, 0, 0);
        }
        asm volatile("s_waitcnt lgkmcnt(0)" ::: "memory");
        __builtin_amdgcn_s_barrier();
        cur ^= 1;
    }

    // epilogue: lane holds 4 consecutive H-cols of one token -> float4 stores
    int w4 = x16 * 4;
    #pragma unroll
    for (int i = 0; i < 2; ++i) {
        int rl = mb + i * 16 + lr;
        int p = m0 + rl;
        if (p < segEnd) {
            int tok = stokL[rl];
            float g = gsL[rl];
            #pragma unroll
            for (int j = 0; j < 4; ++j) {
                int gc = n0 + nb + j * 16 + w4;
                float4 bias = *(const float4*)(b2 + e * H + gc);
                float4 res;
                res.x = g * (acc[i][j][0] + bias.x);
                res.y = g * (acc[i][j][1] + bias.y);
                res.z = g * (acc[i][j][2] + bias.z);
                res.w = g * (acc[i][j][3] + bias.w);
                *(float4*)(out + (size_t)tok * H + gc) = res;
            }
        }
    }
}

extern "C" void kernel_launch(void* const* d_in, const int* in_sizes, int n_in,
                              void* d_out, int out_size, void* d_ws, size_t ws_size,
                              hipStream_t stream) {
    const float* x  = (const float*)d_in[0];
    const float* Wg = (const float*)d_in[1];
    const float* W1 = (const float*)d_in[2];
    const float* b1 = (const float*)d_in[3];
    const float* W2 = (const float*)d_in[4];
    const float* b2 = (const float*)d_in[5];
    float* out = (float*)d_out;

    char* ws = (char*)d_ws;
    unsigned short* xg  = (unsigned short*)(ws + 0);          //  8 MB
    unsigned short* w1t = (unsigned short*)(ws + 8388608);    // 16 MB
    unsigned short* w2t = (unsigned short*)(ws + 25165824);   // 16 MB
    unsigned short* hbf = (unsigned short*)(ws + 41943040);   // 32 MB
    float* gate = (float*)(ws + 75497472);                    // 32 KB
    float* gs   = (float*)(ws + 75530240);                    // 32 KB
    int* stok   = (int*)(ws + 75563008);                      // 32 KB
    int* list   = (int*)(ws + 75595776);                      // 128 KB
    int* cnt    = (int*)(ws + 75726848);                      // 64 B
    float* pprob= (float*)(ws + 75726976);                    // 8 KB

    float* outlb = out + (size_t)NTOK * H;
    hipMemsetAsync(cnt, 0, 8 * sizeof(int), stream);
    router_kernel<<<256, 256, 0, stream>>>(x, Wg, gate, list, cnt, pprob);
    gather_kernel<<<4096, 256, 0, stream>>>(x, gate, list, cnt, pprob, W1, w1t,
                                            xg, gs, stok, outlb);
    gemm1_kernel<<<10240, 256, 0, stream>>>(xg, w1t, b1, cnt, W2, w2t, hbf);
    gemm2_kernel<<<2048, 256, 0, stream>>>(hbf, w2t, b2, cnt, gs, stok, out);
}

// Round 13
// 102.590 us; speedup vs baseline: 1.5222x; 1.0325x over previous
//
#include <hip/hip_runtime.h>
#include <hip/hip_bf16.h>
#include <stdint.h>

#define H 512
#define F 2048
#define E 8
#define NTOK 8192
#define LSTRIDE 4096

typedef __bf16 bf16x8 __attribute__((ext_vector_type(8)));
typedef float f32x4 __attribute__((ext_vector_type(4)));

__device__ __forceinline__ unsigned short f2bf(float f) {
    unsigned u = __builtin_bit_cast(unsigned, f);
    u += 0x7FFFu + ((u >> 16) & 1u);
    return (unsigned short)(u >> 16);
}

__device__ __forceinline__ void gl_lds16(const unsigned short* g, unsigned short* l) {
    __builtin_amdgcn_global_load_lds(
        (const __attribute__((address_space(1))) unsigned int*)g,
        (__attribute__((address_space(3))) unsigned int*)l,
        16, 0, 0);
}

// 64x64 tile transpose via pair-packed LDS (tp = 64*33 u32 = 8448 B scratch)
__device__ __forceinline__ void transpose_tile(const float* __restrict__ src,
                                               unsigned short* __restrict__ dst,
                                               int R, int C, int r0, int c0,
                                               unsigned* tp, int tid) {
    int cg = tid & 15, r2b = tid >> 4;
    #pragma unroll
    for (int p = 0; p < 2; ++p) {
        int r2 = p * 16 + r2b;
        const float* s0 = src + (size_t)(r0 + 2 * r2) * C + c0 + cg * 4;
        float4 v0 = *(const float4*)s0;
        float4 v1 = *(const float4*)(s0 + C);
        tp[(cg * 4 + 0) * 33 + r2] = (unsigned)f2bf(v0.x) | ((unsigned)f2bf(v1.x) << 16);
        tp[(cg * 4 + 1) * 33 + r2] = (unsigned)f2bf(v0.y) | ((unsigned)f2bf(v1.y) << 16);
        tp[(cg * 4 + 2) * 33 + r2] = (unsigned)f2bf(v0.z) | ((unsigned)f2bf(v1.z) << 16);
        tp[(cg * 4 + 3) * 33 + r2] = (unsigned)f2bf(v0.w) | ((unsigned)f2bf(v1.w) << 16);
    }
    __syncthreads();
    int och = tid & 7;
    #pragma unroll
    for (int q = 0; q < 2; ++q) {
        int oc = q * 32 + (tid >> 3);
        uint4 uv;
        uv.x = tp[oc * 33 + och * 4 + 0];
        uv.y = tp[oc * 33 + och * 4 + 1];
        uv.z = tp[oc * 33 + och * 4 + 2];
        uv.w = tp[oc * 33 + och * 4 + 3];
        *(uint4*)(dst + (size_t)(c0 + oc) * R + r0 + och * 8) = uv;
    }
}

// ---------- router (blocks [0,256)) + W1T (256..2304) + W2T (2304..4352) ----------
__global__ void router_kernel(const float* __restrict__ x, const float* __restrict__ Wg,
                              const float* __restrict__ W1, unsigned short* __restrict__ w1t,
                              const float* __restrict__ W2, unsigned short* __restrict__ w2t,
                              float* __restrict__ gate, int* __restrict__ list,
                              int* __restrict__ cnt, float* __restrict__ pprob) {
    __shared__ float wg[H * E];        // router weights; transpose blocks alias as scratch
    __shared__ float lg[32][8];
    __shared__ int am_l[32];
    __shared__ int rank_l[32];
    __shared__ int eb[8];
    int tid = threadIdx.x;

    if (blockIdx.x >= 256) {
        int id = blockIdx.x - 256;
        if (id < 2048) {
            int z = id >> 8;
            int r0 = ((id >> 5) & 7) * 64, c0 = (id & 31) * 64;   // R=512, C=2048
            transpose_tile(W1 + (size_t)z * 512 * 2048, w1t + (size_t)z * 512 * 2048,
                           512, 2048, r0, c0, (unsigned*)wg, tid);
        } else {
            id -= 2048;
            int z = id >> 8;
            int r0 = (id & 31) * 64, c0 = ((id >> 5) & 7) * 64;   // R=2048, C=512
            transpose_tile(W2 + (size_t)z * 2048 * 512, w2t + (size_t)z * 2048 * 512,
                           2048, 512, r0, c0, (unsigned*)wg, tid);
        }
        return;
    }

    int rbid = blockIdx.x;
    #pragma unroll
    for (int p = 0; p < 16; ++p) wg[p * 256 + tid] = Wg[p * 256 + tid];
    __syncthreads();

    int tl = tid >> 3, e = tid & 7;
    int token = rbid * 32 + tl;
    const float4* x4 = (const float4*)(x + (size_t)token * H);
    float acc = 0.f;
    for (int kq = 0; kq < 128; ++kq) {
        float4 v = x4[kq];
        acc += v.x * wg[(kq * 4 + 0) * 8 + e];
        acc += v.y * wg[(kq * 4 + 1) * 8 + e];
        acc += v.z * wg[(kq * 4 + 2) * 8 + e];
        acc += v.w * wg[(kq * 4 + 3) * 8 + e];
    }
    lg[tl][e] = acc;
    __syncthreads();

    if (tid < 32) {
        float l[8];
        #pragma unroll
        for (int q = 0; q < 8; ++q) l[q] = lg[tid][q];
        float mx = l[0];
        #pragma unroll
        for (int q = 1; q < 8; ++q) mx = fmaxf(mx, l[q]);
        float p[8]; float s = 0.f;
        #pragma unroll
        for (int q = 0; q < 8; ++q) { p[q] = expf(l[q] - mx); s += p[q]; }
        int am = 0; float best = l[0];
        #pragma unroll
        for (int q = 1; q < 8; ++q) if (l[q] > best) { best = l[q]; am = q; }
        float inv = 1.f / s;
        #pragma unroll
        for (int q = 0; q < 8; ++q) lg[tid][q] = p[q] * inv;
        float sp = p[am] * inv;
        gate[rbid * 32 + tid] = sp / (sp + 1e-8f);
        am_l[tid] = am;
    }
    __syncthreads();

    if (tid < 8) {
        float s = 0.f;
        for (int i = 0; i < 32; ++i) s += lg[i][tid];
        pprob[rbid * 8 + tid] = s;
        int c = 0;
        for (int i = 0; i < 32; ++i) if (am_l[i] == tid) rank_l[i] = c++;
        eb[tid] = atomicAdd(&cnt[tid], c);
    }
    __syncthreads();

    if (tid < 32) {
        int e2 = am_l[tid];
        int pos = eb[e2] + rank_l[tid];
        if (pos < LSTRIDE) list[e2 * LSTRIDE + pos] = rbid * 32 + tid;
    }
}

__device__ __forceinline__ void load_ebase(const int* __restrict__ cnt, int* eb) {
    int b = 0;
    #pragma unroll
    for (int q = 0; q < 8; ++q) { eb[q] = b; b += cnt[q]; }
}

// ---------- gather: x -> xg (bf16, expert-sorted) + gs/stok; block 0 computes lb ----------
__global__ void gather_kernel(const float* __restrict__ x, const float* __restrict__ gate,
                              const int* __restrict__ list, const int* __restrict__ cnt,
                              const float* __restrict__ pprob,
                              unsigned short* __restrict__ xg, float* __restrict__ gs,
                              int* __restrict__ stok, float* __restrict__ outlb) {
    __shared__ float lbp[8];
    int tid = threadIdx.x;
    int eb[8];
    load_ebase(cnt, eb);
    if (blockIdx.x == 0) {
        if (tid < 8) {
            float acc = 0.f;
            for (int i = 0; i < 256; ++i) acc += pprob[i * 8 + tid];
            lbp[tid] = acc * (float)cnt[tid];
        }
        __syncthreads();
        if (tid == 0) {
            float tot = 0.f;
            #pragma unroll
            for (int q = 0; q < 8; ++q) tot += lbp[q];
            outlb[0] = tot * (8.0f / ((float)NTOK * (float)NTOK));
        }
    }
    int p = blockIdx.x * 4 + (tid >> 6);
    int lane = tid & 63;
    int e = 0;
    #pragma unroll
    for (int q = 1; q < 8; ++q) if (p >= eb[q]) e = q;
    int token = list[e * LSTRIDE + (p - eb[e])];
    const float4* src = (const float4*)(x + (size_t)token * H) + lane * 2;
    float4 a = src[0], b = src[1];
    uint4 u;
    u.x = (unsigned)f2bf(a.x) | ((unsigned)f2bf(a.y) << 16);
    u.y = (unsigned)f2bf(a.z) | ((unsigned)f2bf(a.w) << 16);
    u.z = (unsigned)f2bf(b.x) | ((unsigned)f2bf(b.y) << 16);
    u.w = (unsigned)f2bf(b.z) | ((unsigned)f2bf(b.w) << 16);
    *(uint4*)(xg + (size_t)p * H + lane * 8) = u;
    if (lane == 0) { stok[p] = token; gs[p] = gate[token]; }
}

// ---------- GEMM1: h = relu(xg @ W1t^T + b1), 64x128xBK64, 3/CU, vmcnt(6) ----------
__global__ __launch_bounds__(256, 3) void gemm1_kernel(
    const unsigned short* __restrict__ xg,    // [NTOK][H] sorted
    const unsigned short* __restrict__ w1t,   // [E][F][H]
    const float* __restrict__ b1,
    const int* __restrict__ cnt,
    unsigned short* __restrict__ hbf)         // [NTOK][F] sorted
{
    __shared__ unsigned short Al[2][64 * 64];    // 2 x 8 KB
    __shared__ unsigned short Bl[2][128 * 64];   // 2 x 16 KB
    int tid = threadIdx.x;

    int bid = blockIdx.x;
    int e = bid & 7;                 // expert -> XCD
    int idx = bid >> 3;              // 0..1023
    int mblk = idx >> 4;             // 0..63, m-major
    int c = cnt[e];
    if (mblk * 64 >= c) return;
    int n0 = (idx & 15) * 128;       // n fastest -> same-XCD A-tile reuse
    int eb[8]; load_ebase(cnt, eb);
    int m0 = eb[e] + mblk * 64;
    int segEnd = eb[e] + c;

    int lane = tid & 63, w = tid >> 6;
    int lr8 = lane >> 3, lch = lane & 7;
    int swc = lch ^ lr8;                       // source-side chunk swizzle

    const unsigned short* asrc[2];
    const unsigned short* bsrc[4];
    #pragma unroll
    for (int i = 0; i < 2; ++i) {
        int row = (w * 2 + i) * 8 + lr8;
        int ar = m0 + row; if (ar > NTOK - 1) ar = NTOK - 1;
        asrc[i] = xg + (size_t)ar * H + swc * 8;
    }
    #pragma unroll
    for (int i = 0; i < 4; ++i) {
        int row = (w * 4 + i) * 8 + lr8;
        bsrc[i] = w1t + ((size_t)e * F + n0 + row) * H + swc * 8;
    }

    f32x4 acc[2][4] = {};
    int mb = (w >> 1) * 32, nb = (w & 1) * 64;
    int lr = lane & 15, x16 = lane >> 4;
    int sw = (lr & 7) << 4;                    // read-side byte XOR

    // prologue: 6 loads/thread
    #pragma unroll
    for (int i = 0; i < 2; ++i) gl_lds16(asrc[i], &Al[0][(w * 2 + i) * 512]);
    #pragma unroll
    for (int i = 0; i < 4; ++i) gl_lds16(bsrc[i], &Bl[0][(w * 4 + i) * 512]);

    int cur = 0;
    #pragma unroll
    for (int t = 0; t < 8; ++t) {
        if (t < 7) {
            int k0 = (t + 1) * 64;
            #pragma unroll
            for (int i = 0; i < 2; ++i) gl_lds16(asrc[i] + k0, &Al[cur ^ 1][(w * 2 + i) * 512]);
            #pragma unroll
            for (int i = 0; i < 4; ++i) gl_lds16(bsrc[i] + k0, &Bl[cur ^ 1][(w * 4 + i) * 512]);
            asm volatile("s_waitcnt vmcnt(6)" ::: "memory");   // tile t landed; t+1 in flight
        } else {
            asm volatile("s_waitcnt vmcnt(0)" ::: "memory");
        }
        __builtin_amdgcn_s_barrier();
        #pragma unroll
        for (int kk = 0; kk < 2; ++kk) {
            int co = (kk * 64 + x16 * 16) ^ sw;
            bf16x8 a[2], b[4];
            #pragma unroll
            for (int i = 0; i < 2; ++i)
                a[i] = *(const bf16x8*)((const char*)Al[cur] + (mb + i * 16 + lr) * 128 + co);
            #pragma unroll
            for (int j = 0; j < 4; ++j)
                b[j] = *(const bf16x8*)((const char*)Bl[cur] + (nb + j * 16 + lr) * 128 + co);
            #pragma unroll
            for (int i = 0; i < 2; ++i)
                #pragma unroll
                for (int j = 0; j < 4; ++j)
                    acc[i][j] = __builtin_amdgcn_mfma_f32_16x16x32_bf16(b[j], a[i], acc[i][j], 0, 0, 0);
        }
        asm volatile("s_waitcnt lgkmcnt(0)" ::: "memory");
        __builtin_amdgcn_s_barrier();
        cur ^= 1;
    }

    // epilogue: lane holds 4 consecutive F-cols of one token -> 8B packed stores
    int w4 = x16 * 4;
    #pragma unroll
    for (int j = 0; j < 4; ++j) {
        int gc = n0 + nb + j * 16 + w4;
        float4 bias = *(const float4*)(b1 + e * F + gc);
        #pragma unroll
        for (int i = 0; i < 2; ++i) {
            int p = m0 + mb + i * 16 + lr;
            if (p < segEnd) {
                float v0 = acc[i][j][0] + bias.x; v0 = v0 > 0.f ? v0 : 0.f;
                float v1 = acc[i][j][1] + bias.y; v1 = v1 > 0.f ? v1 : 0.f;
                float v2 = acc[i][j][2] + bias.z; v2 = v2 > 0.f ? v2 : 0.f;
                float v3 = acc[i][j][3] + bias.w; v3 = v3 > 0.f ? v3 : 0.f;
                uint2 pk;
                pk.x = (unsigned)f2bf(v0) | ((unsigned)f2bf(v1) << 16);
                pk.y = (unsigned)f2bf(v2) | ((unsigned)f2bf(v3) << 16);
                *(uint2*)(hbf + (size_t)p * F + gc) = pk;
            }
        }
    }
}

// ---------- GEMM2: out = gate*(h @ W2t^T + b2) scattered, 64x128xBK64, 3/CU, vmcnt(6) ----------
__global__ __launch_bounds__(256, 3) void gemm2_kernel(
    const unsigned short* __restrict__ hbf,   // [NTOK][F] sorted
    const unsigned short* __restrict__ w2t,   // [E][H][F]
    const float* __restrict__ b2,
    const int* __restrict__ cnt,
    const float* __restrict__ gs, const int* __restrict__ stok,
    float* __restrict__ out)                  // [NTOK][H] token order
{
    int bid = blockIdx.x;
    int e = bid & 7;
    int idx = bid >> 3;              // 0..255
    int mblk = idx >> 2;             // 0..63
    int c = cnt[e];
    if (mblk * 64 >= c) return;
    int n0 = (idx & 3) * 128;
    int eb[8]; load_ebase(cnt, eb);
    int m0 = eb[e] + mblk * 64;
    int segEnd = eb[e] + c;

    __shared__ unsigned short Al[2][64 * 64];    // 2 x 8 KB
    __shared__ unsigned short Bl[2][128 * 64];   // 2 x 16 KB
    __shared__ int stokL[64];
    __shared__ float gsL[64];

    int tid = threadIdx.x, lane = tid & 63, w = tid >> 6;
    if (tid < 64) {
        int p = m0 + tid;
        int pc = p > NTOK - 1 ? NTOK - 1 : p;
        stokL[tid] = stok[pc];
        gsL[tid] = gs[pc];
    }
    int lr8 = lane >> 3, lch = lane & 7;
    int swc = lch ^ lr8;

    const unsigned short* asrc[2];
    const unsigned short* bsrc[4];
    #pragma unroll
    for (int i = 0; i < 2; ++i) {
        int row = (w * 2 + i) * 8 + lr8;
        int ar = m0 + row; if (ar > NTOK - 1) ar = NTOK - 1;
        asrc[i] = hbf + (size_t)ar * F + swc * 8;
    }
    #pragma unroll
    for (int i = 0; i < 4; ++i) {
        int row = (w * 4 + i) * 8 + lr8;
        bsrc[i] = w2t + ((size_t)e * H + n0 + row) * F + swc * 8;
    }

    f32x4 acc[2][4] = {};
    int mb = (w >> 1) * 32, nb = (w & 1) * 64;
    int lr = lane & 15, x16 = lane >> 4;
    int sw = (lr & 7) << 4;

    // prologue: 6 loads/thread
    #pragma unroll
    for (int i = 0; i < 2; ++i) gl_lds16(asrc[i], &Al[0][(w * 2 + i) * 512]);
    #pragma unroll
    for (int i = 0; i < 4; ++i) gl_lds16(bsrc[i], &Bl[0][(w * 4 + i) * 512]);
    __builtin_amdgcn_s_barrier();   // stokL/gsL visibility

    int cur = 0;
    #pragma unroll
    for (int t = 0; t < 32; ++t) {
        if (t < 31) {
            int k0 = (t + 1) * 64;
            #pragma unroll
            for (int i = 0; i < 2; ++i) gl_lds16(asrc[i] + k0, &Al[cur ^ 1][(w * 2 + i) * 512]);
            #pragma unroll
            for (int i = 0; i < 4; ++i) gl_lds16(bsrc[i] + k0, &Bl[cur ^ 1][(w * 4 + i) * 512]);
            asm volatile("s_waitcnt vmcnt(6)" ::: "memory");   // tile t landed; t+1 in flight
        } else {
            asm volatile("s_waitcnt vmcnt(0)" ::: "memory");
        }
        __builtin_amdgcn_s_barrier();
        #pragma unroll
        for (int kk = 0; kk < 2; ++kk) {
            int co = (kk * 64 + x16 * 16) ^ sw;
            bf16x8 a[2], b[4];
            #pragma unroll
            for (int i = 0; i < 2; ++i)
                a[i] = *(const bf16x8*)((const char*)Al[cur] + (mb + i * 16 + lr) * 128 + co);
            #pragma unroll
            for (int j = 0; j < 4; ++j)
                b[j] = *(const bf16x8*)((const char*)Bl[cur] + (nb + j * 16 + lr) * 128 + co);
            #pragma unroll
            for (int i = 0; i < 2; ++i)
                #pragma unroll
                for (int j = 0; j < 4; ++j)
                    acc[i][j] = __builtin_amdgcn_mfma_f32_16x16x32_bf16(b[j], a[i], acc[i][j], 0, 0, 0);
        }
        asm volatile("s_waitcnt lgkmcnt(0)" ::: "memory");
        __builtin_amdgcn_s_barrier();
        cur ^= 1;
    }

    // epilogue: lane holds 4 consecutive H-cols of one token -> float4 stores
    int w4 = x16 * 4;
    #pragma unroll
    for (int i = 0; i < 2; ++i) {
        int rl = mb + i * 16 + lr;
        int p = m0 + rl;
        if (p < segEnd) {
            int tok = stokL[rl];
            float g = gsL[rl];
            #pragma unroll
            for (int j = 0; j < 4; ++j) {
                int gc = n0 + nb + j * 16 + w4;
                float4 bias = *(const float4*)(b2 + e * H + gc);
                float4 res;
                res.x = g * (acc[i][j][0] + bias.x);
                res.y = g * (acc[i][j][1] + bias.y);
                res.z = g * (acc[i][j][2] + bias.z);
                res.w = g * (acc[i][j][3] + bias.w);
                *(float4*)(out + (size_t)tok * H + gc) = res;
            }
        }
    }
}

extern "C" void kernel_launch(void* const* d_in, const int* in_sizes, int n_in,
                              void* d_out, int out_size, void* d_ws, size_t ws_size,
                              hipStream_t stream) {
    const float* x  = (const float*)d_in[0];
    const float* Wg = (const float*)d_in[1];
    const float* W1 = (const float*)d_in[2];
    const float* b1 = (const float*)d_in[3];
    const float* W2 = (const float*)d_in[4];
    const float* b2 = (const float*)d_in[5];
    float* out = (float*)d_out;

    char* ws = (char*)d_ws;
    unsigned short* xg  = (unsigned short*)(ws + 0);          //  8 MB
    unsigned short* w1t = (unsigned short*)(ws + 8388608);    // 16 MB
    unsigned short* w2t = (unsigned short*)(ws + 25165824);   // 16 MB
    unsigned short* hbf = (unsigned short*)(ws + 41943040);   // 32 MB
    float* gate = (float*)(ws + 75497472);                    // 32 KB
    float* gs   = (float*)(ws + 75530240);                    // 32 KB
    int* stok   = (int*)(ws + 75563008);                      // 32 KB
    int* list   = (int*)(ws + 75595776);                      // 128 KB
    int* cnt    = (int*)(ws + 75726848);                      // 64 B
    float* pprob= (float*)(ws + 75726976);                    // 8 KB

    float* outlb = out + (size_t)NTOK * H;
    hipMemsetAsync(cnt, 0, 8 * sizeof(int), stream);
    router_kernel<<<4352, 256, 0, stream>>>(x, Wg, W1, w1t, W2, w2t, gate, list, cnt, pprob);
    gather_kernel<<<2048, 256, 0, stream>>>(x, gate, list, cnt, pprob, xg, gs, stok, outlb);
    gemm1_kernel<<<8192, 256, 0, stream>>>(xg, w1t, b1, cnt, hbf);
    gemm2_kernel<<<2048, 256, 0, stream>>>(hbf, w2t, b2, cnt, gs, stok, out);
}

// Round 14
// 97.681 us; speedup vs baseline: 1.5987x; 1.0503x over previous
//
#include <hip/hip_runtime.h>
#include <hip/hip_bf16.h>
#include <stdint.h>

#define H 512
#define F 2048
#define E 8
#define NTOK 8192

typedef __bf16 bf16x8 __attribute__((ext_vector_type(8)));
typedef float f32x4 __attribute__((ext_vector_type(4)));

__device__ __forceinline__ unsigned short f2bf(float f) {
    unsigned u = __builtin_bit_cast(unsigned, f);
    u += 0x7FFFu + ((u >> 16) & 1u);
    return (unsigned short)(u >> 16);
}

__device__ __forceinline__ void gl_lds16(const unsigned short* g, unsigned short* l) {
    __builtin_amdgcn_global_load_lds(
        (const __attribute__((address_space(1))) unsigned int*)g,
        (__attribute__((address_space(3))) unsigned int*)l,
        16, 0, 0);
}

// 64x64 tile transpose via pair-packed LDS (tp = 64*33 u32 = 8448 B scratch)
__device__ __forceinline__ void transpose_tile(const float* __restrict__ src,
                                               unsigned short* __restrict__ dst,
                                               int R, int C, int r0, int c0,
                                               unsigned* tp, int tid) {
    int cg = tid & 15, r2b = tid >> 4;
    #pragma unroll
    for (int p = 0; p < 2; ++p) {
        int r2 = p * 16 + r2b;
        const float* s0 = src + (size_t)(r0 + 2 * r2) * C + c0 + cg * 4;
        float4 v0 = *(const float4*)s0;
        float4 v1 = *(const float4*)(s0 + C);
        tp[(cg * 4 + 0) * 33 + r2] = (unsigned)f2bf(v0.x) | ((unsigned)f2bf(v1.x) << 16);
        tp[(cg * 4 + 1) * 33 + r2] = (unsigned)f2bf(v0.y) | ((unsigned)f2bf(v1.y) << 16);
        tp[(cg * 4 + 2) * 33 + r2] = (unsigned)f2bf(v0.z) | ((unsigned)f2bf(v1.z) << 16);
        tp[(cg * 4 + 3) * 33 + r2] = (unsigned)f2bf(v0.w) | ((unsigned)f2bf(v1.w) << 16);
    }
    __syncthreads();
    int och = tid & 7;
    #pragma unroll
    for (int q = 0; q < 2; ++q) {
        int oc = q * 32 + (tid >> 3);
        uint4 uv;
        uv.x = tp[oc * 33 + och * 4 + 0];
        uv.y = tp[oc * 33 + och * 4 + 1];
        uv.z = tp[oc * 33 + och * 4 + 2];
        uv.w = tp[oc * 33 + och * 4 + 3];
        *(uint4*)(dst + (size_t)(c0 + oc) * R + r0 + och * 8) = uv;
    }
}

// ---------- router (blocks [0,256)) + W1T (256..2304) + W2T (2304..4352) ----------
// No atomics: writes am[], bcnt[rb][e], gate[], pprob[rb][e].
__global__ void router_kernel(const float* __restrict__ x, const float* __restrict__ Wg,
                              const float* __restrict__ W1, unsigned short* __restrict__ w1t,
                              const float* __restrict__ W2, unsigned short* __restrict__ w2t,
                              float* __restrict__ gate, int* __restrict__ am,
                              int* __restrict__ bcnt, float* __restrict__ pprob) {
    __shared__ float wg[H * E];        // router weights; transpose blocks alias as scratch
    __shared__ float lg[32][8];
    __shared__ int am_l[32];
    int tid = threadIdx.x;

    if (blockIdx.x >= 256) {
        int id = blockIdx.x - 256;
        if (id < 2048) {
            int z = id >> 8;
            int r0 = ((id >> 5) & 7) * 64, c0 = (id & 31) * 64;   // R=512, C=2048
            transpose_tile(W1 + (size_t)z * 512 * 2048, w1t + (size_t)z * 512 * 2048,
                           512, 2048, r0, c0, (unsigned*)wg, tid);
        } else {
            id -= 2048;
            int z = id >> 8;
            int r0 = (id & 31) * 64, c0 = ((id >> 5) & 7) * 64;   // R=2048, C=512
            transpose_tile(W2 + (size_t)z * 2048 * 512, w2t + (size_t)z * 2048 * 512,
                           2048, 512, r0, c0, (unsigned*)wg, tid);
        }
        return;
    }

    int rbid = blockIdx.x;
    #pragma unroll
    for (int p = 0; p < 16; ++p) wg[p * 256 + tid] = Wg[p * 256 + tid];
    __syncthreads();

    int tl = tid >> 3, e = tid & 7;
    int token = rbid * 32 + tl;
    const float4* x4 = (const float4*)(x + (size_t)token * H);
    float acc = 0.f;
    for (int kq = 0; kq < 128; ++kq) {
        float4 v = x4[kq];
        acc += v.x * wg[(kq * 4 + 0) * 8 + e];
        acc += v.y * wg[(kq * 4 + 1) * 8 + e];
        acc += v.z * wg[(kq * 4 + 2) * 8 + e];
        acc += v.w * wg[(kq * 4 + 3) * 8 + e];
    }
    lg[tl][e] = acc;
    __syncthreads();

    if (tid < 32) {
        float l[8];
        #pragma unroll
        for (int q = 0; q < 8; ++q) l[q] = lg[tid][q];
        float mx = l[0];
        #pragma unroll
        for (int q = 1; q < 8; ++q) mx = fmaxf(mx, l[q]);
        float p[8]; float s = 0.f;
        #pragma unroll
        for (int q = 0; q < 8; ++q) { p[q] = expf(l[q] - mx); s += p[q]; }
        int amv = 0; float best = l[0];
        #pragma unroll
        for (int q = 1; q < 8; ++q) if (l[q] > best) { best = l[q]; amv = q; }
        float inv = 1.f / s;
        #pragma unroll
        for (int q = 0; q < 8; ++q) lg[tid][q] = p[q] * inv;
        float sp = p[amv] * inv;
        gate[rbid * 32 + tid] = sp / (sp + 1e-8f);
        am_l[tid] = amv;
        am[rbid * 32 + tid] = amv;
    }
    __syncthreads();

    if (tid < 8) {
        float s = 0.f;
        int c = 0;
        for (int i = 0; i < 32; ++i) {
            s += lg[i][tid];
            if (am_l[i] == tid) c++;
        }
        pprob[rbid * 8 + tid] = s;
        bcnt[rbid * 8 + tid] = c;
    }
}

// ---------- gather: arithmetic placement from bcnt/am; scatter x -> xg; block0: cnt + lb ----------
__global__ void gather_kernel(const float* __restrict__ x, const float* __restrict__ gate,
                              const int* __restrict__ am, const int* __restrict__ bcnt,
                              const float* __restrict__ pprob,
                              unsigned short* __restrict__ xg, float* __restrict__ gs,
                              int* __restrict__ stok, int* __restrict__ cnt,
                              float* __restrict__ outlb) {
    __shared__ int bc[2048];       // 8 KB: all per-router-block counts
    __shared__ int totalL[8], offL[8], ebaseL[8];
    __shared__ int amL[32], posL[32];
    int tid = threadIdx.x;
    int rb = blockIdx.x >> 3;      // router block 0..255
    int part = blockIdx.x & 7;     // 4 tokens per part

    #pragma unroll
    for (int k = 0; k < 8; ++k) bc[tid * 8 + k] = bcnt[tid * 8 + k];
    if (tid < 32) amL[tid] = am[rb * 32 + tid];
    __syncthreads();

    if (tid < 8) {
        int s = 0, off = 0;
        for (int r = 0; r < 256; ++r) {
            if (r == rb) off = s;
            s += bc[r * 8 + tid];
        }
        totalL[tid] = s;
        offL[tid] = off;
    }
    __syncthreads();
    if (tid == 0) {
        int b = 0;
        #pragma unroll
        for (int q = 0; q < 8; ++q) { ebaseL[q] = b; b += totalL[q]; }
    }
    __syncthreads();
    if (tid < 32) {
        int e = amL[tid];
        int rank = 0;
        for (int j = 0; j < 32; ++j) if (j < tid && amL[j] == e) rank++;
        posL[tid] = ebaseL[e] + offL[e] + rank;
    }
    __syncthreads();

    if (blockIdx.x == 0) {
        if (tid < 8) {
            float acc = 0.f;
            for (int i = 0; i < 256; ++i) acc += pprob[i * 8 + tid];
            // stash partial in bc (reuse LDS)
            ((float*)bc)[tid] = acc * (float)totalL[tid];
            cnt[tid] = totalL[tid];
        }
        __syncthreads();
        if (tid == 0) {
            float tot = 0.f;
            #pragma unroll
            for (int q = 0; q < 8; ++q) tot += ((float*)bc)[q];
            outlb[0] = tot * (8.0f / ((float)NTOK * (float)NTOK));
        }
    }

    int i = part * 4 + (tid >> 6);          // token index within router block
    int lane = tid & 63;
    int token = rb * 32 + i;
    int pos = posL[i];
    const float4* src = (const float4*)(x + (size_t)token * H) + lane * 2;
    float4 a = src[0], b = src[1];
    uint4 u;
    u.x = (unsigned)f2bf(a.x) | ((unsigned)f2bf(a.y) << 16);
    u.y = (unsigned)f2bf(a.z) | ((unsigned)f2bf(a.w) << 16);
    u.z = (unsigned)f2bf(b.x) | ((unsigned)f2bf(b.y) << 16);
    u.w = (unsigned)f2bf(b.z) | ((unsigned)f2bf(b.w) << 16);
    *(uint4*)(xg + (size_t)pos * H + lane * 8) = u;
    if (lane == 0) { stok[pos] = token; gs[pos] = gate[token]; }
}

__device__ __forceinline__ void load_ebase(const int* __restrict__ cnt, int* eb) {
    int b = 0;
    #pragma unroll
    for (int q = 0; q < 8; ++q) { eb[q] = b; b += cnt[q]; }
}

// ---------- GEMM1: h = relu(xg @ W1t^T + b1), 64x128xBK64, 3/CU, vmcnt(6) ----------
__global__ __launch_bounds__(256, 3) void gemm1_kernel(
    const unsigned short* __restrict__ xg,    // [NTOK][H] sorted
    const unsigned short* __restrict__ w1t,   // [E][F][H]
    const float* __restrict__ b1,
    const int* __restrict__ cnt,
    unsigned short* __restrict__ hbf)         // [NTOK][F] sorted
{
    __shared__ unsigned short Al[2][64 * 64];    // 2 x 8 KB
    __shared__ unsigned short Bl[2][128 * 64];   // 2 x 16 KB
    int tid = threadIdx.x;

    int bid = blockIdx.x;
    int e = bid & 7;                 // expert -> XCD
    int idx = bid >> 3;              // 0..1023
    int mblk = idx >> 4;             // 0..63, m-major
    int c = cnt[e];
    if (mblk * 64 >= c) return;
    int n0 = (idx & 15) * 128;       // n fastest -> same-XCD A-tile reuse
    int eb[8]; load_ebase(cnt, eb);
    int m0 = eb[e] + mblk * 64;
    int segEnd = eb[e] + c;

    int lane = tid & 63, w = tid >> 6;
    int lr8 = lane >> 3, lch = lane & 7;
    int swc = lch ^ lr8;                       // source-side chunk swizzle

    const unsigned short* asrc[2];
    const unsigned short* bsrc[4];
    #pragma unroll
    for (int i = 0; i < 2; ++i) {
        int row = (w * 2 + i) * 8 + lr8;
        int ar = m0 + row; if (ar > NTOK - 1) ar = NTOK - 1;
        asrc[i] = xg + (size_t)ar * H + swc * 8;
    }
    #pragma unroll
    for (int i = 0; i < 4; ++i) {
        int row = (w * 4 + i) * 8 + lr8;
        bsrc[i] = w1t + ((size_t)e * F + n0 + row) * H + swc * 8;
    }

    f32x4 acc[2][4] = {};
    int mb = (w >> 1) * 32, nb = (w & 1) * 64;
    int lr = lane & 15, x16 = lane >> 4;
    int sw = (lr & 7) << 4;                    // read-side byte XOR

    // prologue: 6 loads/thread
    #pragma unroll
    for (int i = 0; i < 2; ++i) gl_lds16(asrc[i], &Al[0][(w * 2 + i) * 512]);
    #pragma unroll
    for (int i = 0; i < 4; ++i) gl_lds16(bsrc[i], &Bl[0][(w * 4 + i) * 512]);

    int cur = 0;
    #pragma unroll
    for (int t = 0; t < 8; ++t) {
        if (t < 7) {
            int k0 = (t + 1) * 64;
            #pragma unroll
            for (int i = 0; i < 2; ++i) gl_lds16(asrc[i] + k0, &Al[cur ^ 1][(w * 2 + i) * 512]);
            #pragma unroll
            for (int i = 0; i < 4; ++i) gl_lds16(bsrc[i] + k0, &Bl[cur ^ 1][(w * 4 + i) * 512]);
            asm volatile("s_waitcnt vmcnt(6)" ::: "memory");   // tile t landed; t+1 in flight
        } else {
            asm volatile("s_waitcnt vmcnt(0)" ::: "memory");
        }
        __builtin_amdgcn_s_barrier();
        #pragma unroll
        for (int kk = 0; kk < 2; ++kk) {
            int co = (kk * 64 + x16 * 16) ^ sw;
            bf16x8 a[2], b[4];
            #pragma unroll
            for (int i = 0; i < 2; ++i)
                a[i] = *(const bf16x8*)((const char*)Al[cur] + (mb + i * 16 + lr) * 128 + co);
            #pragma unroll
            for (int j = 0; j < 4; ++j)
                b[j] = *(const bf16x8*)((const char*)Bl[cur] + (nb + j * 16 + lr) * 128 + co);
            #pragma unroll
            for (int i = 0; i < 2; ++i)
                #pragma unroll
                for (int j = 0; j < 4; ++j)
                    acc[i][j] = __builtin_amdgcn_mfma_f32_16x16x32_bf16(b[j], a[i], acc[i][j], 0, 0, 0);
        }
        asm volatile("s_waitcnt lgkmcnt(0)" ::: "memory");
        __builtin_amdgcn_s_barrier();
        cur ^= 1;
    }

    // epilogue: lane holds 4 consecutive F-cols of one token -> 8B packed stores
    int w4 = x16 * 4;
    #pragma unroll
    for (int j = 0; j < 4; ++j) {
        int gc = n0 + nb + j * 16 + w4;
        float4 bias = *(const float4*)(b1 + e * F + gc);
        #pragma unroll
        for (int i = 0; i < 2; ++i) {
            int p = m0 + mb + i * 16 + lr;
            if (p < segEnd) {
                float v0 = acc[i][j][0] + bias.x; v0 = v0 > 0.f ? v0 : 0.f;
                float v1 = acc[i][j][1] + bias.y; v1 = v1 > 0.f ? v1 : 0.f;
                float v2 = acc[i][j][2] + bias.z; v2 = v2 > 0.f ? v2 : 0.f;
                float v3 = acc[i][j][3] + bias.w; v3 = v3 > 0.f ? v3 : 0.f;
                uint2 pk;
                pk.x = (unsigned)f2bf(v0) | ((unsigned)f2bf(v1) << 16);
                pk.y = (unsigned)f2bf(v2) | ((unsigned)f2bf(v3) << 16);
                *(uint2*)(hbf + (size_t)p * F + gc) = pk;
            }
        }
    }
}

// ---------- GEMM2: out = gate*(h @ W2t^T + b2) scattered, 64x128xBK64, 3/CU, vmcnt(6) ----------
__global__ __launch_bounds__(256, 3) void gemm2_kernel(
    const unsigned short* __restrict__ hbf,   // [NTOK][F] sorted
    const unsigned short* __restrict__ w2t,   // [E][H][F]
    const float* __restrict__ b2,
    const int* __restrict__ cnt,
    const float* __restrict__ gs, const int* __restrict__ stok,
    float* __restrict__ out)                  // [NTOK][H] token order
{
    int bid = blockIdx.x;
    int e = bid & 7;
    int idx = bid >> 3;              // 0..255
    int mblk = idx >> 2;             // 0..63
    int c = cnt[e];
    if (mblk * 64 >= c) return;
    int n0 = (idx & 3) * 128;
    int eb[8]; load_ebase(cnt, eb);
    int m0 = eb[e] + mblk * 64;
    int segEnd = eb[e] + c;

    __shared__ unsigned short Al[2][64 * 64];    // 2 x 8 KB
    __shared__ unsigned short Bl[2][128 * 64];   // 2 x 16 KB
    __shared__ int stokL[64];
    __shared__ float gsL[64];

    int tid = threadIdx.x, lane = tid & 63, w = tid >> 6;
    if (tid < 64) {
        int p = m0 + tid;
        int pc = p > NTOK - 1 ? NTOK - 1 : p;
        stokL[tid] = stok[pc];
        gsL[tid] = gs[pc];
    }
    int lr8 = lane >> 3, lch = lane & 7;
    int swc = lch ^ lr8;

    const unsigned short* asrc[2];
    const unsigned short* bsrc[4];
    #pragma unroll
    for (int i = 0; i < 2; ++i) {
        int row = (w * 2 + i) * 8 + lr8;
        int ar = m0 + row; if (ar > NTOK - 1) ar = NTOK - 1;
        asrc[i] = hbf + (size_t)ar * F + swc * 8;
    }
    #pragma unroll
    for (int i = 0; i < 4; ++i) {
        int row = (w * 4 + i) * 8 + lr8;
        bsrc[i] = w2t + ((size_t)e * H + n0 + row) * F + swc * 8;
    }

    f32x4 acc[2][4] = {};
    int mb = (w >> 1) * 32, nb = (w & 1) * 64;
    int lr = lane & 15, x16 = lane >> 4;
    int sw = (lr & 7) << 4;

    // prologue: 6 loads/thread
    #pragma unroll
    for (int i = 0; i < 2; ++i) gl_lds16(asrc[i], &Al[0][(w * 2 + i) * 512]);
    #pragma unroll
    for (int i = 0; i < 4; ++i) gl_lds16(bsrc[i], &Bl[0][(w * 4 + i) * 512]);
    __builtin_amdgcn_s_barrier();   // stokL/gsL visibility

    int cur = 0;
    #pragma unroll
    for (int t = 0; t < 32; ++t) {
        if (t < 31) {
            int k0 = (t + 1) * 64;
            #pragma unroll
            for (int i = 0; i < 2; ++i) gl_lds16(asrc[i] + k0, &Al[cur ^ 1][(w * 2 + i) * 512]);
            #pragma unroll
            for (int i = 0; i < 4; ++i) gl_lds16(bsrc[i] + k0, &Bl[cur ^ 1][(w * 4 + i) * 512]);
            asm volatile("s_waitcnt vmcnt(6)" ::: "memory");   // tile t landed; t+1 in flight
        } else {
            asm volatile("s_waitcnt vmcnt(0)" ::: "memory");
        }
        __builtin_amdgcn_s_barrier();
        #pragma unroll
        for (int kk = 0; kk < 2; ++kk) {
            int co = (kk * 64 + x16 * 16) ^ sw;
            bf16x8 a[2], b[4];
            #pragma unroll
            for (int i = 0; i < 2; ++i)
                a[i] = *(const bf16x8*)((const char*)Al[cur] + (mb + i * 16 + lr) * 128 + co);
            #pragma unroll
            for (int j = 0; j < 4; ++j)
                b[j] = *(const bf16x8*)((const char*)Bl[cur] + (nb + j * 16 + lr) * 128 + co);
            #pragma unroll
            for (int i = 0; i < 2; ++i)
                #pragma unroll
                for (int j = 0; j < 4; ++j)
                    acc[i][j] = __builtin_amdgcn_mfma_f32_16x16x32_bf16(b[j], a[i], acc[i][j], 0, 0, 0);
        }
        asm volatile("s_waitcnt lgkmcnt(0)" ::: "memory");
        __builtin_amdgcn_s_barrier();
        cur ^= 1;
    }

    // epilogue: lane holds 4 consecutive H-cols of one token -> float4 stores
    int w4 = x16 * 4;
    #pragma unroll
    for (int i = 0; i < 2; ++i) {
        int rl = mb + i * 16 + lr;
        int p = m0 + rl;
        if (p < segEnd) {
            int tok = stokL[rl];
            float g = gsL[rl];
            #pragma unroll
            for (int j = 0; j < 4; ++j) {
                int gc = n0 + nb + j * 16 + w4;
                float4 bias = *(const float4*)(b2 + e * H + gc);
                float4 res;
                res.x = g * (acc[i][j][0] + bias.x);
                res.y = g * (acc[i][j][1] + bias.y);
                res.z = g * (acc[i][j][2] + bias.z);
                res.w = g * (acc[i][j][3] + bias.w);
                *(float4*)(out + (size_t)tok * H + gc) = res;
            }
        }
    }
}

extern "C" void kernel_launch(void* const* d_in, const int* in_sizes, int n_in,
                              void* d_out, int out_size, void* d_ws, size_t ws_size,
                              hipStream_t stream) {
    const float* x  = (const float*)d_in[0];
    const float* Wg = (const float*)d_in[1];
    const float* W1 = (const float*)d_in[2];
    const float* b1 = (const float*)d_in[3];
    const float* W2 = (const float*)d_in[4];
    const float* b2 = (const float*)d_in[5];
    float* out = (float*)d_out;

    char* ws = (char*)d_ws;
    unsigned short* xg  = (unsigned short*)(ws + 0);          //  8 MB
    unsigned short* w1t = (unsigned short*)(ws + 8388608);    // 16 MB
    unsigned short* w2t = (unsigned short*)(ws + 25165824);   // 16 MB
    unsigned short* hbf = (unsigned short*)(ws + 41943040);   // 32 MB
    float* gate = (float*)(ws + 75497472);                    // 32 KB
    float* gs   = (float*)(ws + 75530240);                    // 32 KB
    int* stok   = (int*)(ws + 75563008);                      // 32 KB
    int* am     = (int*)(ws + 75595776);                      // 32 KB
    int* bcnt   = (int*)(ws + 75628544);                      // 8 KB
    int* cnt    = (int*)(ws + 75726848);                      // 64 B
    float* pprob= (float*)(ws + 75726976);                    // 8 KB

    float* outlb = out + (size_t)NTOK * H;
    router_kernel<<<4352, 256, 0, stream>>>(x, Wg, W1, w1t, W2, w2t, gate, am, bcnt, pprob);
    gather_kernel<<<2048, 256, 0, stream>>>(x, gate, am, bcnt, pprob, xg, gs, stok, cnt, outlb);
    gemm1_kernel<<<8192, 256, 0, stream>>>(xg, w1t, b1, cnt, hbf);
    gemm2_kernel<<<2048, 256, 0, stream>>>(hbf, w2t, b2, cnt, gs, stok, out);
}